// Round 9
// baseline (371.112 us; speedup 1.0000x reference)
//
#include <hip/hip_runtime.h>
#include <cmath>

#define B_   32
#define N_   512
#define E_   8192
#define BN_  16384
#define D_   128

typedef short bf16x8 __attribute__((ext_vector_type(8)));
typedef float f32x4  __attribute__((ext_vector_type(4)));

static __device__ __forceinline__ float bf2f(unsigned short u){
  union{unsigned int i; float f;} v; v.i = ((unsigned int)u)<<16; return v.f;
}
static __device__ __forceinline__ unsigned short f2bf(float f){
  union{unsigned int i; float f;} v; v.f=f;
  unsigned int x=v.i;
  return (unsigned short)((x + 0x7fffu + ((x>>16)&1u))>>16);
}
static __device__ __forceinline__ unsigned int pack2(float a, float b){
  return (unsigned int)f2bf(a) | ((unsigned int)f2bf(b)<<16);
}
// precise GELU (A&S erf, |err|<=1.5e-7) - cold paths
static __device__ __forceinline__ float gelu_f(float x){
  float xs=x*0.70710678118654752f;
  float ax=fabsf(xs);
  float t=__builtin_amdgcn_rcpf(1.0f+0.3275911f*ax);
  float p=t*(0.254829592f+t*(-0.284496736f+t*(1.421413741f+t*(-1.453152027f+t*1.061405429f))));
  float er=1.0f - p*__expf(-ax*ax);
  er = (xs<0.f)? -er : er;
  return 0.5f*x*(1.0f+er);
}
// tanh-form GELU: x/(1+e^{x(c1+c2 x^2)}), |dev from erf-gelu|<=3e-4 (<< bf16 noise) - hot path
static __device__ __forceinline__ float gelu_t(float x){
  float x2=x*x;
  float y=x*(-1.5957691216f + x2*(-0.0713548162f));
  float e=__expf(y);
  return x*__builtin_amdgcn_rcpf(1.0f+e);
}
static __device__ __forceinline__ float ldin(const void* p, size_t i, int isbf){
  return isbf ? bf2f(((const unsigned short*)p)[i]) : ((const float*)p)[i];
}

static __device__ __forceinline__ void block_sum2(float a, float b, float&A, float&Bv, float* red, int nw){
  int lane=threadIdx.x&63, w=threadIdx.x>>6;
  #pragma unroll
  for(int o=32;o>0;o>>=1){ a+=__shfl_down(a,o); b+=__shfl_down(b,o); }
  if(lane==0){ red[w]=a; red[8+w]=b; }
  __syncthreads();
  float sa=0.f, sb=0.f;
  for(int i=0;i<nw;i++){ sa+=red[i]; sb+=red[8+i]; }
  __syncthreads();
  A=sa; Bv=sb;
}

// ---------------- fused sort (hist + scan + scatter) + dtype sniff ----------------
// blocks 0..31 (1024 thr, 16 waves): counting sort of graph g's edges by dst. block 32: sniff.
__global__ __launch_bounds__(1024) void sort_kernel(
  const int* __restrict__ src, const int* __restrict__ dst,
  int* __restrict__ rowptr, unsigned short* __restrict__ ss,
  const unsigned int* __restrict__ xw, int* __restrict__ flag)
{
  int t=threadIdx.x;
  if(blockIdx.x==32){
    if(t<64){
      int cnt=0;
      for(int i=0;i<32;i++){
        unsigned int w=xw[t+64*i];
        float v=bf2f((unsigned short)(w&0xffffu));
        float av=fabsf(v);
        if(v==0.0f || (av>=6e-5f && av<=8.0f)) cnt++;
      }
      #pragma unroll
      for(int o=32;o>0;o>>=1) cnt+=__shfl_down(cnt,o);
      if(t==0) *flag=(cnt>=1024)?1:0;
    }
    return;
  }
  __shared__ int cnts[512];
  __shared__ int offs[512];
  __shared__ int wred[8];
  int g=blockIdx.x;
  if(t<512) cnts[t]=0;
  __syncthreads();
  const int* dg=dst+(size_t)g*E_;
  #pragma unroll
  for(int e=t;e<E_;e+=1024) atomicAdd(&cnts[dg[e]],1);
  __syncthreads();
  // block exclusive scan over 512 counters: threads 0..255, thread t owns {2t, 2t+1}
  if(t<256){
    int lane=t&63, w=t>>6;
    int c0=cnts[2*t], c1=cnts[2*t+1];
    int mysum=c0+c1;
    int sc=mysum;
    #pragma unroll
    for(int o=1;o<64;o<<=1){ int v=__shfl_up(sc,o); if(lane>=o) sc+=v; }
    if(lane==63) wred[w]=sc;
    __syncthreads();
    int wbase=0;
    for(int i=0;i<w;i++) wbase+=wred[i];
    int excl=wbase+sc-mysum;
    rowptr[g*513+2*t  ]=excl;
    rowptr[g*513+2*t+1]=excl+c0;
    offs[2*t  ]=excl;
    offs[2*t+1]=excl+c0;
    if(t==255) rowptr[g*513+512]=wbase+sc;
  } else {
    __syncthreads();
  }
  __syncthreads();
  const int* sg=src+(size_t)g*E_;
  unsigned short* ssg=ss+(size_t)g*E_;
  #pragma unroll
  for(int e=t;e<E_;e+=1024){
    int d=dg[e];
    int pos=atomicAdd(&offs[d],1);
    ssg[pos]=(unsigned short)sg[e];
  }
}

// cb layout (bf16 canonical):
// [0,1152) qkv bias | [1152,1536) ob | [1536,1920) msg_b1 | [1920,2304) msg_b2
// [2304,2688) msg_g | [2688,3072) msg_bb | [3072,3456) attn_g | [3456,3840) attn_b
// [3840,4096) enc_b1 | [4096,4352) enc_g1 | [4352,4608) enc_bn1
// [4608,4736) enc_b2 | [4736,4864) enc_g2 | [4864,4992) enc_bn2
// [4992,5248) gh_b1 | [5248,5504) gh_g | [5504,5760) gh_bn | [5760,5776) gh_b2
__global__ __launch_bounds__(256) void prep_kernel(
  const void* __restrict__ msg_w1, const void* __restrict__ msg_w2,
  const void* __restrict__ qw, const void* __restrict__ kw,
  const void* __restrict__ vw, const void* __restrict__ ow,
  const void* __restrict__ qb, const void* __restrict__ kb, const void* __restrict__ vb,
  const void* __restrict__ ob, const void* __restrict__ msg_b1, const void* __restrict__ msg_b2,
  const void* __restrict__ msg_g, const void* __restrict__ msg_bb,
  const void* __restrict__ attn_g, const void* __restrict__ attn_b,
  const void* __restrict__ enc_w1, const void* __restrict__ enc_w2,
  const void* __restrict__ enc_b1, const void* __restrict__ enc_g1, const void* __restrict__ enc_bn1,
  const void* __restrict__ enc_b2, const void* __restrict__ enc_g2, const void* __restrict__ enc_bn2,
  const void* __restrict__ gh_w1, const void* __restrict__ gh_w2,
  const void* __restrict__ gh_b1, const void* __restrict__ gh_g,
  const void* __restrict__ gh_bn, const void* __restrict__ gh_b2,
  unsigned short* __restrict__ w1t, unsigned short* __restrict__ w2k,
  unsigned short* __restrict__ qkvt, unsigned short* __restrict__ owt,
  unsigned short* __restrict__ w1te, unsigned short* __restrict__ w2te,
  unsigned short* __restrict__ ghw1t, unsigned short* __restrict__ ghw2t,
  unsigned short* __restrict__ cb, const int* __restrict__ flag)
{
  int isbf=*flag;
  int job=blockIdx.y;
  int i=blockIdx.x*256+threadIdx.x;
  if(job<3){ // msg_w1[l] [256][128] -> [128][256] n-major
    if(i<32768){ int l=job; int k=i>>7, n=i&127; w1t[l*32768 + n*256 + k]=f2bf(ldin(msg_w1,(size_t)l*32768+i,isbf)); }
  } else if(job<6){ // msg_w2[l] straight copy [128k][128n]
    int l=job-3; if(i<16384){ w2k[l*16384 + i]=f2bf(ldin(msg_w2,(size_t)l*16384+i,isbf)); }
  } else if(job<15){
    int r=job-6, l=r/3, which=r%3;
    if(i<16384){ int k=i>>7, n=i&127;
      const void* w=(which==0)?qw:((which==1)?kw:vw);
      qkvt[l*49152 + (which*128+n)*128 + k]=f2bf(ldin(w,(size_t)l*16384+i,isbf)); }
  } else if(job<18){
    int l=job-15; if(i<16384){ int k=i>>7, n=i&127; owt[l*16384 + n*128 + k]=f2bf(ldin(ow,(size_t)l*16384+i,isbf)); }
  } else if(job==18){
    if(i<3840){
      float v;
      if(i<1152){ int l=i/384, j=i%384, which=j>>7, jj=j&127;
        const void* bb=(which==0)?qb:((which==1)?kb:vb);
        v=ldin(bb,(size_t)l*128+jj,isbf);
      } else {
        int i2=i-1152; int r=i2/384; int rem=i2%384;
        const void* s = (r==0)?ob:((r==1)?msg_b1:((r==2)?msg_b2:((r==3)?msg_g:((r==4)?msg_bb:((r==5)?attn_g:attn_b)))));
        v=ldin(s,(size_t)rem,isbf);
      }
      cb[i]=f2bf(v);
    }
  } else if(job==19){
    if(i<1152){
      float v;
      if(i<256)       v=ldin(enc_b1,i,isbf);
      else if(i<512)  v=ldin(enc_g1,i-256,isbf);
      else if(i<768)  v=ldin(enc_bn1,i-512,isbf);
      else if(i<896)  v=ldin(enc_b2,i-768,isbf);
      else if(i<1024) v=ldin(enc_g2,i-896,isbf);
      else            v=ldin(enc_bn2,i-1024,isbf);
      cb[3840+i]=f2bf(v);
    }
  } else if(job==20){
    if(i<16384){ int k=i>>8, n=i&255; w1te[n*64+k]=f2bf(ldin(enc_w1,(size_t)i,isbf)); }
  } else if(job==21){
    if(i<32768){ int k=i>>7, n=i&127; w2te[n*256+k]=f2bf(ldin(enc_w2,(size_t)i,isbf)); }
  } else if(job<26){
    int p=job-22; int j=p*32768+i;
    if(i<32768){ int k=j>>8, n=j&255; ghw1t[n*512+k]=f2bf(ldin(gh_w1,(size_t)j,isbf)); }
  } else {
    if(i<2560){ int k=i/10, n=i%10; ghw2t[n*256+k]=f2bf(ldin(gh_w2,(size_t)i,isbf)); }
    else if(i<2560+778){
      int j=i-2560; float v;
      if(j<256)      v=ldin(gh_b1,j,isbf);
      else if(j<512) v=ldin(gh_g,j-256,isbf);
      else if(j<768) v=ldin(gh_bn,j-512,isbf);
      else           v=ldin(gh_b2,j-768,isbf);
      cb[4992+j]=f2bf(v);
    }
  }
}

// ---------------- fused node encoder (+ layer-0 UV generation) ----------------
__global__ __launch_bounds__(256) void enc_kernel(
  const void* __restrict__ x, const unsigned short* __restrict__ w1te,
  const unsigned short* __restrict__ w2te, const unsigned short* __restrict__ cb,
  unsigned short* __restrict__ h, const int* __restrict__ flag,
  const unsigned short* __restrict__ w1t0, unsigned short* __restrict__ UV)
{
  __shared__ __align__(16) unsigned short xs[64][72];
  __shared__ __align__(16) unsigned short t1[64][264];
  int isbf=*flag;
  int m0=blockIdx.x*64;
  int t=threadIdx.x, lane=t&63, w=t>>6, quad=lane>>4, ln=lane&15;
  for(int c2=t;c2<1024;c2+=256){
    int i=c2*4, row=i>>6, col=i&63;
    float v0,v1,v2,v3;
    if(isbf){
      const unsigned short* p=(const unsigned short*)x+(size_t)m0*64+i;
      v0=bf2f(p[0]); v1=bf2f(p[1]); v2=bf2f(p[2]); v3=bf2f(p[3]);
    } else {
      float4 f=*(const float4*)((const float*)x+(size_t)m0*64+i);
      v0=f.x; v1=f.y; v2=f.z; v3=f.w;
    }
    ushort4 o; o.x=f2bf(v0); o.y=f2bf(v1); o.z=f2bf(v2); o.w=f2bf(v3);
    *(ushort4*)&xs[row][col]=o;
  }
  __syncthreads();
  f32x4 a[4][4];
  #pragma unroll
  for(int nt=0;nt<4;nt++){ a[nt][0]={0,0,0,0}; a[nt][1]={0,0,0,0}; a[nt][2]={0,0,0,0}; a[nt][3]={0,0,0,0}; }
  #pragma unroll
  for(int k0i=0;k0i<2;k0i++){
    bf16x8 af[4];
    #pragma unroll
    for(int f=0;f<4;f++) af[f]=*(const bf16x8*)(&xs[f*16+ln][k0i*32+quad*8]);
    #pragma unroll
    for(int nt=0;nt<4;nt++){
      int n=w*64+nt*16+ln;
      bf16x8 bfr=*(const bf16x8*)(w1te+(size_t)n*64+k0i*32+quad*8);
      #pragma unroll
      for(int f=0;f<4;f++) a[nt][f]=__builtin_amdgcn_mfma_f32_16x16x32_bf16(af[f],bfr,a[nt][f],0,0,0);
    }
  }
  #pragma unroll
  for(int nt=0;nt<4;nt++){
    int n=w*64+nt*16+ln;
    float bv=bf2f(cb[3840+n]);
    #pragma unroll
    for(int f=0;f<4;f++)
      #pragma unroll
      for(int r=0;r<4;r++) t1[f*16+quad*4+r][n]=f2bf(a[nt][f][r]+bv);
  }
  __syncthreads();
  {
    int row=t>>2, qq=t&3;
    float s=0.f,s2=0.f;
    for(int c=qq*64;c<qq*64+64;c++){ float v=bf2f(t1[row][c]); s+=v; s2+=v*v; }
    s+=__shfl_xor(s,1); s+=__shfl_xor(s,2);
    s2+=__shfl_xor(s2,1); s2+=__shfl_xor(s2,2);
    float mu=s*(1.f/256.f), var=fmaxf(s2*(1.f/256.f)-mu*mu,0.f);
    float rr=rsqrtf(var+1e-5f);
    for(int c=qq*64;c<qq*64+64;c++){
      float v=bf2f(t1[row][c]);
      t1[row][c]=f2bf(gelu_f((v-mu)*rr*bf2f(cb[4096+c])+bf2f(cb[4352+c])));
    }
  }
  __syncthreads();
  f32x4 b2a[2][4];
  #pragma unroll
  for(int nt=0;nt<2;nt++){ b2a[nt][0]={0,0,0,0}; b2a[nt][1]={0,0,0,0}; b2a[nt][2]={0,0,0,0}; b2a[nt][3]={0,0,0,0}; }
  #pragma unroll
  for(int k0i=0;k0i<8;k0i++){
    bf16x8 af[4];
    #pragma unroll
    for(int f=0;f<4;f++) af[f]=*(const bf16x8*)(&t1[f*16+ln][k0i*32+quad*8]);
    #pragma unroll
    for(int nt=0;nt<2;nt++){
      int n=w*32+nt*16+ln;
      bf16x8 bfr=*(const bf16x8*)(w2te+(size_t)n*256+k0i*32+quad*8);
      #pragma unroll
      for(int f=0;f<4;f++) b2a[nt][f]=__builtin_amdgcn_mfma_f32_16x16x32_bf16(af[f],bfr,b2a[nt][f],0,0,0);
    }
  }
  __syncthreads();
  float* mf=(float*)&t1[0][0];   // [64][132]
  #pragma unroll
  for(int nt=0;nt<2;nt++){
    int n=w*32+nt*16+ln;
    float bv=bf2f(cb[4608+n]);
    #pragma unroll
    for(int f=0;f<4;f++)
      #pragma unroll
      for(int r=0;r<4;r++) mf[(f*16+quad*4+r)*132+n]=b2a[nt][f][r]+bv;
  }
  __syncthreads();
  {
    int row=t>>2, qq=t&3;
    float vals[32];
    float s=0.f,s2=0.f;
    for(int j=0;j<32;j++){ float v=mf[row*132+qq*32+j]; vals[j]=v; s+=v; s2+=v*v; }
    s+=__shfl_xor(s,1); s+=__shfl_xor(s,2);
    s2+=__shfl_xor(s2,1); s2+=__shfl_xor(s2,2);
    float mu=s*(1.f/128.f), var=fmaxf(s2*(1.f/128.f)-mu*mu,0.f);
    float rr=rsqrtf(var+1e-5f);
    for(int j=0;j<32;j+=2){
      int c=qq*32+j;
      float v0=(vals[j]  -mu)*rr*bf2f(cb[4736+c  ])+bf2f(cb[4864+c  ]);
      float v1=(vals[j+1]-mu)*rr*bf2f(cb[4736+c+1])+bf2f(cb[4864+c+1]);
      *(unsigned int*)(h+(size_t)(m0+row)*128+c)=pack2(v0,v1);
      vals[j]=v0; vals[j+1]=v1;
    }
    __syncthreads();   // all mf reads done before t1 reuse as hb
    unsigned short* hb=&t1[0][0];  // [64][136] bf16
    for(int j=0;j<32;j++) hb[row*136+qq*32+j]=f2bf(vals[j]);
  }
  __syncthreads();
  // ---- fused uvgen for layer 0: UV[m0..m0+64) = [h@W1a+b1 | h@W1b] ----
  {
    const unsigned short* hb=&t1[0][0];
    #pragma unroll
    for(int y=0;y<2;y++)
    #pragma unroll
    for(int nt=0;nt<2;nt++){
      int n=w*32+nt*16+ln;
      f32x4 a0={0,0,0,0},a1={0,0,0,0},a2={0,0,0,0},a3={0,0,0,0};
      const unsigned short* wp=w1t0+(size_t)n*256+y*128+quad*8;
      #pragma unroll
      for(int k0=0;k0<128;k0+=32){
        bf16x8 bfr=*(const bf16x8*)(wp+k0);
        bf16x8 f0=*(const bf16x8*)(hb+(size_t)(ln   )*136+k0+quad*8);
        bf16x8 f1=*(const bf16x8*)(hb+(size_t)(16+ln)*136+k0+quad*8);
        bf16x8 f2=*(const bf16x8*)(hb+(size_t)(32+ln)*136+k0+quad*8);
        bf16x8 f3=*(const bf16x8*)(hb+(size_t)(48+ln)*136+k0+quad*8);
        a0=__builtin_amdgcn_mfma_f32_16x16x32_bf16(f0,bfr,a0,0,0,0);
        a1=__builtin_amdgcn_mfma_f32_16x16x32_bf16(f1,bfr,a1,0,0,0);
        a2=__builtin_amdgcn_mfma_f32_16x16x32_bf16(f2,bfr,a2,0,0,0);
        a3=__builtin_amdgcn_mfma_f32_16x16x32_bf16(f3,bfr,a3,0,0,0);
      }
      float bv=y?0.f:bf2f(cb[1536+n]);
      #pragma unroll
      for(int r=0;r<4;r++){
        UV[(size_t)(m0   +quad*4+r)*256+y*128+n]=f2bf(a0[r]+bv);
        UV[(size_t)(m0+16+quad*4+r)*256+y*128+n]=f2bf(a1[r]+bv);
        UV[(size_t)(m0+32+quad*4+r)*256+y*128+n]=f2bf(a2[r]+bv);
        UV[(size_t)(m0+48+quad*4+r)*256+y*128+n]=f2bf(a3[r]+bv);
      }
    }
  }
}

// ---------------- QKV generation: Q (pre-scaled, row-major), K (row-major), V^T ----------------
// grid (gA*8, 3): y=0 -> Q, y=1 -> K, y=2 -> V written transposed [g][128 dims][512 keys]
__global__ __launch_bounds__(256) void qkvgen_kernel(
  const unsigned short* __restrict__ hrows, const unsigned short* __restrict__ wqkv,
  const unsigned short* __restrict__ bqkv,
  unsigned short* __restrict__ Qb, unsigned short* __restrict__ Kb,
  unsigned short* __restrict__ Vtb)
{
  __shared__ __align__(16) unsigned short a_t[64][136];
  int t=threadIdx.x;
  int m0=blockIdx.x*64;
  int y=blockIdx.y;
  for(int c=t;c<1024;c+=256){
    int m=c>>4, pp=c&15;
    *(uint4*)&a_t[m][pp*8]=*((const uint4*)(hrows+(size_t)(m0+m)*128)+pp);
  }
  __syncthreads();
  int lane=t&63, w=t>>6, quad=lane>>4, ln=lane&15;
  int gloc=m0>>9, r0=m0&511;
  #pragma unroll
  for(int nt=0;nt<2;nt++){
    int n=w*32+nt*16+ln;
    f32x4 a0={0,0,0,0},a1={0,0,0,0},a2={0,0,0,0},a3={0,0,0,0};
    const unsigned short* wp=wqkv+(size_t)(y*128+n)*128+quad*8;
    #pragma unroll
    for(int k0=0;k0<128;k0+=32){
      bf16x8 bfr=*(const bf16x8*)(wp+k0);
      bf16x8 f0=*(const bf16x8*)(&a_t[ln   ][k0+quad*8]);
      bf16x8 f1=*(const bf16x8*)(&a_t[16+ln][k0+quad*8]);
      bf16x8 f2=*(const bf16x8*)(&a_t[32+ln][k0+quad*8]);
      bf16x8 f3=*(const bf16x8*)(&a_t[48+ln][k0+quad*8]);
      a0=__builtin_amdgcn_mfma_f32_16x16x32_bf16(f0,bfr,a0,0,0,0);
      a1=__builtin_amdgcn_mfma_f32_16x16x32_bf16(f1,bfr,a1,0,0,0);
      a2=__builtin_amdgcn_mfma_f32_16x16x32_bf16(f2,bfr,a2,0,0,0);
      a3=__builtin_amdgcn_mfma_f32_16x16x32_bf16(f3,bfr,a3,0,0,0);
    }
    float bv=bf2f(bqkv[y*128+n]);
    if(y==0){
      const float sc=0.17677669529663689f;
      #pragma unroll
      for(int r=0;r<4;r++){
        Qb[(size_t)(m0   +quad*4+r)*128+n]=f2bf((a0[r]+bv)*sc);
        Qb[(size_t)(m0+16+quad*4+r)*128+n]=f2bf((a1[r]+bv)*sc);
        Qb[(size_t)(m0+32+quad*4+r)*128+n]=f2bf((a2[r]+bv)*sc);
        Qb[(size_t)(m0+48+quad*4+r)*128+n]=f2bf((a3[r]+bv)*sc);
      }
    } else if(y==1){
      #pragma unroll
      for(int r=0;r<4;r++){
        Kb[(size_t)(m0   +quad*4+r)*128+n]=f2bf(a0[r]+bv);
        Kb[(size_t)(m0+16+quad*4+r)*128+n]=f2bf(a1[r]+bv);
        Kb[(size_t)(m0+32+quad*4+r)*128+n]=f2bf(a2[r]+bv);
        Kb[(size_t)(m0+48+quad*4+r)*128+n]=f2bf(a3[r]+bv);
      }
    } else {
      unsigned short* vrow = Vtb + ((size_t)gloc*128+n)*512 + r0 + quad*4;
      ushort4 o;
      o.x=f2bf(a0[0]+bv); o.y=f2bf(a0[1]+bv); o.z=f2bf(a0[2]+bv); o.w=f2bf(a0[3]+bv);
      *(ushort4*)(vrow)=o;
      o.x=f2bf(a1[0]+bv); o.y=f2bf(a1[1]+bv); o.z=f2bf(a1[2]+bv); o.w=f2bf(a1[3]+bv);
      *(ushort4*)(vrow+16)=o;
      o.x=f2bf(a2[0]+bv); o.y=f2bf(a2[1]+bv); o.z=f2bf(a2[2]+bv); o.w=f2bf(a2[3]+bv);
      *(ushort4*)(vrow+32)=o;
      o.x=f2bf(a3[0]+bv); o.y=f2bf(a3[1]+bv); o.z=f2bf(a3[2]+bv); o.w=f2bf(a3[3]+bv);
      *(ushort4*)(vrow+48)=o;
    }
  }
}

// ---------------- fused edge phase: branchless gather (fast gelu) + k-split GEMV ----------------
__global__ __launch_bounds__(128) void edgef_kernel(
  unsigned short* __restrict__ h,
  const unsigned short* __restrict__ UV,      // full rows [B*512][256], global-g indexed
  const unsigned short* __restrict__ ss,
  const int* __restrict__ rowptr,
  const unsigned short* __restrict__ w2k,     // [128k][128n]
  const unsigned short* __restrict__ b2,
  const unsigned short* __restrict__ gg, const unsigned short* __restrict__ bbp,
  int b0, int gEp)
{
  __shared__ __align__(16) float aggL[2][4][128];
  __shared__ __align__(16) float po[2][4][128];
  int t=threadIdx.x, lane=t&63, w=t>>6;
  int bid=blockIdx.x;
  int lg=bid%gEp, ch=bid/gEp;     // ch in [0,128): 4-dst chunk
  int g=b0+lg;
  const unsigned short* UVg = UV + (size_t)g*512*256;
  const unsigned short* ssg = ss + (size_t)g*E_;
  int dbase = ch*4;
  int bnd[5];
  #pragma unroll
  for(int i=0;i<5;i++) bnd[i]=rowptr[g*513+dbase+i];
  // ---- gather: wave w takes its half of each dst's edge range (branchless, masked idx) ----
  #pragma unroll 1
  for(int dd=0;dd<4;dd++){
    int e_lo=bnd[dd], e_hi0=bnd[dd+1];
    int half=(e_hi0-e_lo+1)>>1;
    int es = w ? (e_lo+half) : e_lo;
    int ee = w ? e_hi0       : (e_lo+half);
    unsigned int vdw=*(const unsigned int*)(UVg + (size_t)(dbase+dd)*256 + 128 + lane*2);
    float v0=bf2f((unsigned short)(vdw&0xffffu)), v1=bf2f((unsigned short)(vdw>>16));
    float a0=0.f, a1=0.f;
    int si3,si4,si5;
    unsigned int u0,u1,u2;
    {
      // over-reads (<=6 u16 past range) stay in-ws; idx masked &511
      int s0=__builtin_amdgcn_readfirstlane((int)ssg[es  ])&511;
      int s1=__builtin_amdgcn_readfirstlane((int)ssg[es+1])&511;
      int s2=__builtin_amdgcn_readfirstlane((int)ssg[es+2])&511;
      si3=(int)ssg[es+3]; si4=(int)ssg[es+4]; si5=(int)ssg[es+5];
      u0=*(const unsigned int*)(UVg + (size_t)s0*256 + lane*2);
      u1=*(const unsigned int*)(UVg + (size_t)s1*256 + lane*2);
      u2=*(const unsigned int*)(UVg + (size_t)s2*256 + lane*2);
    }
    #pragma unroll 2
    for(int e=es;e<ee;e++){
      float z0=bf2f((unsigned short)(u0&0xffffu))+v0;
      float z1=bf2f((unsigned short)(u0>>16))+v1;
      u0=u1; u1=u2;
      int s3=__builtin_amdgcn_readfirstlane(si3)&511;
      u2=*(const unsigned int*)(UVg + (size_t)s3*256 + lane*2);
      si3=si4; si4=si5;
      si5=(int)ssg[e+6];
      a0+=gelu_t(z0); a1+=gelu_t(z1);
    }
    aggL[w][dd][lane*2  ]=a0;
    aggL[w][dd][lane*2+1]=a1;
  }
  __syncthreads();
  // ---- GEMV k-split: wave w does all 4 dst over k in [w*64, w*64+64) ----
  float o[4][2];
  #pragma unroll
  for(int dd=0;dd<4;dd++){ o[dd][0]=0.f; o[dd][1]=0.f; }
  #pragma unroll 4
  for(int kk=0;kk<64;kk++){
    int k=w*64+kk;
    unsigned int wdw=*(const unsigned int*)(w2k+(size_t)k*128+lane*2);
    float w0=bf2f((unsigned short)(wdw&0xffffu));
    float w1=bf2f((unsigned short)(wdw>>16));
    #pragma unroll
    for(int dd=0;dd<4;dd++){
      float av=aggL[0][dd][k]+aggL[1][dd][k];
      o[dd][0]+=av*w0; o[dd][1]+=av*w1;
    }
  }
  #pragma unroll
  for(int dd=0;dd<4;dd++){
    po[w][dd][lane*2  ]=o[dd][0];
    po[w][dd][lane*2+1]=o[dd][1];
  }
  __syncthreads();
  // ---- combine partials + deg*b2 + residual + LN: wave w owns dst pair {2w, 2w+1} ----
  #pragma unroll 1
  for(int p=0;p<2;p++){
    int di=w*2+p;
    int d = dbase + di;
    float deg=(float)(bnd[di+1]-bnd[di]);
    float o0=bf2f(b2[lane*2  ])*deg + po[0][di][lane*2  ] + po[1][di][lane*2  ];
    float o1=bf2f(b2[lane*2+1])*deg + po[0][di][lane*2+1] + po[1][di][lane*2+1];
    size_t base=(size_t)(g*512+d)*128;
    unsigned int hdw=*(const unsigned int*)(h+base+lane*2);
    float x0=bf2f((unsigned short)(hdw&0xffffu))+o0;
    float x1=bf2f((unsigned short)(hdw>>16))+o1;
    float s1=x0+x1, s2=x0*x0+x1*x1;
    #pragma unroll
    for(int off=32;off>0;off>>=1){ s1+=__shfl_xor(s1,off); s2+=__shfl_xor(s2,off); }
    float mu=s1*(1.f/128.f), var=fmaxf(s2*(1.f/128.f)-mu*mu,0.f);
    float rr=rsqrtf(var+1e-5f);
    float y0=(x0-mu)*rr*bf2f(gg[lane*2  ])+bf2f(bbp[lane*2  ]);
    float y1=(x1-mu)*rr*bf2f(gg[lane*2+1])+bf2f(bbp[lane*2+1]);
    *(unsigned int*)(h+base+lane*2)=pack2(y0,y1);
  }
}

// ---------------- fused flash attention + oproj + residual/LN + next-layer uvgen / pool partials ----------------
// grid gA*16: block = (graph lg, 32-row tile ch). wave w = head w. barrier-free flash.
// K/V register prefetch (1-deep) hides global-load latency. P->bf16 stays the manual RNE f2bf
// (R8 lesson: v_cvt_pk_bf16_f32's rounding is NOT RNE-equivalent -> absmax blew past threshold).
__global__ __launch_bounds__(256) void attn_fused_kernel(
  const unsigned short* __restrict__ Qb, const unsigned short* __restrict__ Kb,
  const unsigned short* __restrict__ Vtb,
  const unsigned short* __restrict__ wo, const unsigned short* __restrict__ bo,
  unsigned short* __restrict__ h,
  const unsigned short* __restrict__ gg, const unsigned short* __restrict__ bbp,
  const unsigned short* __restrict__ w1tn, const unsigned short* __restrict__ b1n,
  unsigned short* __restrict__ UV, float* part, int b0, int gA, int do_uv)
{
  __shared__ __align__(16) unsigned short hO[32][136];
  __shared__ __align__(16) unsigned short Psh[2][4][16][72];
  __shared__ __align__(16) float mf[32][132];
  int bx=blockIdx.x;
  int lg=bx%gA, ch=bx/gA;           // ch in [0,16)
  int r0=ch*32;
  int g=b0+lg;
  int t=threadIdx.x, lane=t&63, w=t>>6, quad=lane>>4, ln=lane&15;
  const unsigned short* Qg = Qb + (size_t)lg*65536;
  const unsigned short* Kg = Kb + (size_t)lg*65536 + w*32;
  const unsigned short* Vg = Vtb + ((size_t)lg*128 + w*32)*512;
  // ---- flash: wave w = head w, rows [r0, r0+32) ----
  bf16x8 qf[2];
  #pragma unroll
  for(int qt=0;qt<2;qt++)
    qf[qt]=*(const bf16x8*)(Qg + (size_t)(r0+qt*16+ln)*128 + w*32 + quad*8);
  f32x4 O[2][2]; float Lp[2][4];
  #pragma unroll
  for(int qt=0;qt<2;qt++){ O[qt][0]={0,0,0,0}; O[qt][1]={0,0,0,0};
    #pragma unroll
    for(int r=0;r<4;r++) Lp[qt][r]=0.f; }
  bf16x8 kf[4], va[2], vb[2];
  #pragma unroll
  for(int f=0;f<4;f++) kf[f]=*(const bf16x8*)(Kg + (size_t)(f*16+ln)*128 + quad*8);
  #pragma unroll
  for(int s2=0;s2<2;s2++){
    va[s2]=*(const bf16x8*)(Vg + (size_t)ln*512      + s2*32 + quad*8);
    vb[s2]=*(const bf16x8*)(Vg + (size_t)(16+ln)*512 + s2*32 + quad*8);
  }
  for(int kc=0;kc<8;kc++){
    // prefetch next kc's K/V fragments (branchless wrap; kc=7 redundantly reloads kc=0)
    int kn=(kc+1)&7;
    bf16x8 kfn[4], van[2], vbn[2];
    #pragma unroll
    for(int f=0;f<4;f++) kfn[f]=*(const bf16x8*)(Kg + (size_t)(kn*64+f*16+ln)*128 + quad*8);
    #pragma unroll
    for(int s2=0;s2<2;s2++){
      van[s2]=*(const bf16x8*)(Vg + (size_t)ln*512      + kn*64 + s2*32 + quad*8);
      vbn[s2]=*(const bf16x8*)(Vg + (size_t)(16+ln)*512 + kn*64 + s2*32 + quad*8);
    }
    #pragma unroll
    for(int qt=0;qt<2;qt++){
      f32x4 s[4];
      #pragma unroll
      for(int f=0;f<4;f++){
        f32x4 z={0,0,0,0};
        s[f]=__builtin_amdgcn_mfma_f32_16x16x32_bf16(qf[qt],kf[f],z,0,0,0);
      }
      #pragma unroll
      for(int f=0;f<4;f++)
        #pragma unroll
        for(int r=0;r<4;r++){
          float pe=__expf(fminf(s[f][r],30.0f));
          Psh[qt][w][quad*4+r][f*16+ln]=f2bf(pe);
          Lp[qt][r]+=pe;
        }
      #pragma unroll
      for(int s2=0;s2<2;s2++){
        bf16x8 pf=*(const bf16x8*)(&Psh[qt][w][ln][s2*32+quad*8]);
        O[qt][0]=__builtin_amdgcn_mfma_f32_16x16x32_bf16(pf,va[s2],O[qt][0],0,0,0);
        O[qt][1]=__builtin_amdgcn_mfma_f32_16x16x32_bf16(pf,vb[s2],O[qt][1],0,0,0);
      }
    }
    #pragma unroll
    for(int f=0;f<4;f++) kf[f]=kfn[f];
    #pragma unroll
    for(int s2=0;s2<2;s2++){ va[s2]=van[s2]; vb[s2]=vbn[s2]; }
  }
  #pragma unroll
  for(int qt=0;qt<2;qt++){
    #pragma unroll
    for(int o=1;o<16;o<<=1)
      #pragma unroll
      for(int r=0;r<4;r++) Lp[qt][r]+=__shfl_xor(Lp[qt][r],o);
    #pragma unroll
    for(int r=0;r<4;r++){
      float inv=1.0f/Lp[qt][r];
      int qr=qt*16+quad*4+r;
      hO[qr][w*32+ln   ]=f2bf(O[qt][0][r]*inv);
      hO[qr][w*32+16+ln]=f2bf(O[qt][1][r]*inv);
    }
  }
  __syncthreads();
  // ---- oproj GEMM on the 32-row tile ----
  #pragma unroll
  for(int nt=0;nt<2;nt++){
    int n=w*32+nt*16+ln;
    f32x4 a0={0,0,0,0},a1={0,0,0,0};
    const unsigned short* wp=wo+(size_t)n*128+quad*8;
    #pragma unroll
    for(int k0=0;k0<128;k0+=32){
      bf16x8 bfr=*(const bf16x8*)(wp+k0);
      bf16x8 f0=*(const bf16x8*)(&hO[ln   ][k0+quad*8]);
      bf16x8 f1=*(const bf16x8*)(&hO[16+ln][k0+quad*8]);
      a0=__builtin_amdgcn_mfma_f32_16x16x32_bf16(f0,bfr,a0,0,0,0);
      a1=__builtin_amdgcn_mfma_f32_16x16x32_bf16(f1,bfr,a1,0,0,0);
    }
    float bv=bf2f(bo[n]);
    #pragma unroll
    for(int r=0;r<4;r++){
      mf[quad*4+r   ][n]=a0[r]+bv;
      mf[16+quad*4+r][n]=a1[r]+bv;
    }
  }
  __syncthreads();
  // ---- residual + LN; write h, refill hO (bf16) and mf (f32) with new-h ----
  {
    int row=t>>3, oct=t&7;
    size_t base=((size_t)(g*512+r0+row))*128;
    float vals[16];
    float s=0.f,s2=0.f;
    for(int j=0;j<16;j++){
      int c=oct*16+j;
      float v=bf2f(h[base+c])+mf[row][c];
      vals[j]=v; s+=v; s2+=v*v;
    }
    s+=__shfl_xor(s,1); s+=__shfl_xor(s,2); s+=__shfl_xor(s,4);
    s2+=__shfl_xor(s2,1); s2+=__shfl_xor(s2,2); s2+=__shfl_xor(s2,4);
    float mu=s*(1.f/128.f), var=fmaxf(s2*(1.f/128.f)-mu*mu,0.f);
    float rr=rsqrtf(var+1e-5f);
    for(int j=0;j<16;j+=2){
      int c=oct*16+j;
      float y0=(vals[j]  -mu)*rr*bf2f(gg[c  ])+bf2f(bbp[c  ]);
      float y1=(vals[j+1]-mu)*rr*bf2f(gg[c+1])+bf2f(bbp[c+1]);
      *(unsigned int*)(h+base+c)=pack2(y0,y1);
      hO[row][c]=f2bf(y0); hO[row][c+1]=f2bf(y1);
      mf[row][c]=y0; mf[row][c+1]=y1;
    }
  }
  __syncthreads();
  if(!do_uv){
    // ---- pool partials for this 32-row tile ----
    if(t<128){
      float s=0.f,s2=0.f,mx=-1e30f;
      for(int r=0;r<32;r++){ float v=mf[r][t]; s+=v; s2+=v*v; mx=fmaxf(mx,v); }
      size_t pb=((size_t)(g*16+ch))*384;
      part[pb+t]=s; part[pb+128+t]=s2; part[pb+256+t]=mx;
    }
    return;
  }
  // ---- next-layer uvgen on the 32-row tile ----
  #pragma unroll
  for(int y=0;y<2;y++)
  #pragma unroll
  for(int nt=0;nt<2;nt++){
    int n=w*32+nt*16+ln;
    f32x4 a0={0,0,0,0},a1={0,0,0,0};
    const unsigned short* wp=w1tn+(size_t)n*256+y*128+quad*8;
    #pragma unroll
    for(int k0=0;k0<128;k0+=32){
      bf16x8 bfr=*(const bf16x8*)(wp+k0);
      bf16x8 f0=*(const bf16x8*)(&hO[ln   ][k0+quad*8]);
      bf16x8 f1=*(const bf16x8*)(&hO[16+ln][k0+quad*8]);
      a0=__builtin_amdgcn_mfma_f32_16x16x32_bf16(f0,bfr,a0,0,0,0);
      a1=__builtin_amdgcn_mfma_f32_16x16x32_bf16(f1,bfr,a1,0,0,0);
    }
    float bv=y?0.f:bf2f(b1n[n]);
    size_t rb=(size_t)(g*512+r0);
    #pragma unroll
    for(int r=0;r<4;r++){
      UV[(rb   +quad*4+r)*256+y*128+n]=f2bf(a0[r]+bv);
      UV[(rb+16+quad*4+r)*256+y*128+n]=f2bf(a1[r]+bv);
    }
  }
}

// ---------------- graph head: finalize pooling + MLP ----------------
__global__ __launch_bounds__(256) void head_kernel(
  const float* __restrict__ part, const unsigned short* __restrict__ ghw1t,
  const unsigned short* __restrict__ ghw2t, const unsigned short* __restrict__ cb,
  void* __restrict__ out, const int* __restrict__ flag)
{
  int isbf=*flag;
  int b=blockIdx.x, t=threadIdx.x;
  __shared__ float pl[512];
  __shared__ float gl[256];
  __shared__ float red[16];
  if(t<128){
    float s=0.f,s2=0.f,mx=-1e30f;
    for(int c=0;c<16;c++){
      size_t base=((size_t)(b*16+c))*384;
      s += part[base+t];
      s2+= part[base+128+t];
      mx = fmaxf(mx, part[base+256+t]);
    }
    float mean=s*(1.f/512.f);
    float var=fmaxf(s2*(1.f/512.f)-mean*mean,0.f);
    float sd=sqrtf(var+1e-6f);
    pl[t]=mean; pl[128+t]=s; pl[256+t]=mx; pl[384+t]=sd;
  }
  __syncthreads();
  float a=bf2f(cb[4992+t]);
  const unsigned short* wr=ghw1t+(size_t)t*512;
  for(int k0=0;k0<512;k0+=8){
    bf16x8 wv=*(const bf16x8*)(wr+k0);
    const unsigned short* wp=(const unsigned short*)&wv;
    #pragma unroll
    for(int j=0;j<8;j++) a+=pl[k0+j]*bf2f(wp[j]);
  }
  float u=gelu_f(a);
  float S,S2; block_sum2(u,u*u,S,S2,red,4);
  float mu=S*(1.f/256.f), var=fmaxf(S2*(1.f/256.f)-mu*mu,0.f);
  float r=rsqrtf(var+1e-5f);
  gl[t]=(u-mu)*r*bf2f(cb[5248+t])+bf2f(cb[5504+t]);
  __syncthreads();
  if(t<10){
    float o=bf2f(cb[5760+t]);
    const unsigned short* wr2=ghw2t+(size_t)t*256;
    for(int k0=0;k0<256;k0+=8){
      bf16x8 wv=*(const bf16x8*)(wr2+k0);
      const unsigned short* wp=(const unsigned short*)&wv;
      #pragma unroll
      for(int j=0;j<8;j++) o+=gl[k0+j]*bf2f(wp[j]);
    }
    if(isbf) ((unsigned short*)out)[b*10+t]=f2bf(o);
    else     ((float*)out)[b*10+t]=o;
  }
}

extern "C" void kernel_launch(void* const* d_in, const int* in_sizes, int n_in,
                              void* d_out, int out_size, void* d_ws, size_t ws_size,
                              hipStream_t stream)
{
  const void* x      =d_in[0];
  const int*  src    =(const int*)d_in[1];
  const int*  dstp   =(const int*)d_in[2];
  const void* enc_w1 =d_in[3];  const void* enc_b1 =d_in[4];
  const void* enc_g1 =d_in[5];  const void* enc_bn1=d_in[6];
  const void* enc_w2 =d_in[7];  const void* enc_b2 =d_in[8];
  const void* enc_g2 =d_in[9];  const void* enc_bn2=d_in[10];
  const void* msg_w1 =d_in[11]; const void* msg_b1 =d_in[12];
  const void* msg_w2 =d_in[13]; const void* msg_b2 =d_in[14];
  const void* msg_g  =d_in[15]; const void* msg_bb =d_in[16];
  const void* qw     =d_in[17]; const void* qb     =d_in[18];
  const void* kw     =d_in[19]; const void* kb     =d_in[20];
  const void* vw     =d_in[21]; const void* vb     =d_in[22];
  const void* ow     =d_in[23]; const void* ob     =d_in[24];
  const void* attn_g =d_in[25]; const void* attn_b =d_in[26];
  const void* gh_w1  =d_in[27]; const void* gh_b1  =d_in[28];
  const void* gh_g   =d_in[29]; const void* gh_bn  =d_in[30];
  const void* gh_w2  =d_in[31]; const void* gh_b2  =d_in[32];
  (void)in_sizes; (void)n_in; (void)out_size;

  char* base=(char*)d_ws;
  unsigned short* h    =(unsigned short*)(base);                 // 4 MB
  unsigned short* w1t  =(unsigned short*)(base + 4194304);
  unsigned short* w2k  =(unsigned short*)(base + 4390912);
  unsigned short* qkvt =(unsigned short*)(base + 4489216);
  unsigned short* owt  =(unsigned short*)(base + 4784128);
  unsigned short* w1te =(unsigned short*)(base + 4882432);
  unsigned short* w2te =(unsigned short*)(base + 4915200);
  unsigned short* ghw1t=(unsigned short*)(base + 4980736);
  unsigned short* ghw2t=(unsigned short*)(base + 5242880);
  unsigned short* cb   =(unsigned short*)(base + 5248000);
  int*   rowptr        =(int*)(base + 5325312);                  // 65664 B
  int*   flag          =(int*)(base + 5390976);
  unsigned short* ssrt =(unsigned short*)(base + 5505024);       // 512 KB (+edgef over-reads land in R)
  char* R              = base + 6029312;                          // shared region

  // R layout: UV (full, 8 MB) | Qb | Kb | Vtb  (per attn pass, gA graphs each)
  size_t Rcap = (ws_size > 6029312) ? (ws_size - 6029312) : 0;
  int gA = 32;
  while(gA > 4 && 8388608 + (size_t)gA*393216 > Rcap) gA >>= 1;
  int apass = 32/gA;
  unsigned short* UV  =(unsigned short*)R;                  // 16384 x 256 bf16 = 8 MB
  unsigned short* Qb  =UV  + 4194304;                       // gA*512*128 bf16
  unsigned short* Kb  =Qb  + (size_t)gA*65536;
  unsigned short* Vtb =Kb  + (size_t)gA*65536;
  float* part=(float*)R;   // pool partials: 32*16*384*4 = 786 KB (UV region free during l==2 attn)

  sort_kernel<<<33,1024,0,stream>>>(src,dstp,rowptr,ssrt,(const unsigned int*)x,flag);
  prep_kernel<<<dim3(128,27),256,0,stream>>>(msg_w1,msg_w2,qw,kw,vw,ow,qb,kb,vb,
      ob,msg_b1,msg_b2,msg_g,msg_bb,attn_g,attn_b,
      enc_w1,enc_w2,enc_b1,enc_g1,enc_bn1,enc_b2,enc_g2,enc_bn2,
      gh_w1,gh_w2,gh_b1,gh_g,gh_bn,gh_b2,
      w1t,w2k,qkvt,owt,w1te,w2te,ghw1t,ghw2t,cb,flag);

  enc_kernel<<<BN_/64,256,0,stream>>>(x,w1te,w2te,cb,h,flag,w1t,UV);

  for(int l=0;l<3;l++){
    edgef_kernel<<<32*128,128,0,stream>>>(h,UV,ssrt,rowptr,
        w2k+(size_t)l*16384, cb+1920+l*128, cb+2304+l*128, cb+2688+l*128, 0, 32);
    int ln=(l+1)%3;
    for(int ap=0;ap<apass;ap++){
      int b0=ap*gA;
      qkvgen_kernel<<<dim3(gA*8,3),256,0,stream>>>(h+(size_t)b0*512*128,
          qkvt+(size_t)l*49152, cb+l*384, Qb, Kb, Vtb);
      attn_fused_kernel<<<gA*16,256,0,stream>>>(Qb, Kb, Vtb,
          owt+(size_t)l*16384, cb+1152+l*128, h, cb+3072+l*128, cb+3456+l*128,
          w1t+(size_t)ln*32768, cb+1536+ln*128, UV, part, b0, gA, (l<2)?1:0);
    }
  }
  head_kernel<<<B_,256,0,stream>>>(part,ghw1t,ghw2t,cb,d_out,flag);
}

// Round 10
// 365.648 us; speedup vs baseline: 1.0149x; 1.0149x over previous
//
#include <hip/hip_runtime.h>
#include <cmath>

#define B_   32
#define N_   512
#define E_   8192
#define BN_  16384
#define D_   128

typedef short bf16x8 __attribute__((ext_vector_type(8)));
typedef float f32x4  __attribute__((ext_vector_type(4)));

static __device__ __forceinline__ float bf2f(unsigned short u){
  union{unsigned int i; float f;} v; v.i = ((unsigned int)u)<<16; return v.f;
}
static __device__ __forceinline__ unsigned short f2bf(float f){
  union{unsigned int i; float f;} v; v.f=f;
  unsigned int x=v.i;
  return (unsigned short)((x + 0x7fffu + ((x>>16)&1u))>>16);
}
static __device__ __forceinline__ unsigned int pack2(float a, float b){
  return (unsigned int)f2bf(a) | ((unsigned int)f2bf(b)<<16);
}
// precise GELU (A&S erf, |err|<=1.5e-7) - cold paths
static __device__ __forceinline__ float gelu_f(float x){
  float xs=x*0.70710678118654752f;
  float ax=fabsf(xs);
  float t=__builtin_amdgcn_rcpf(1.0f+0.3275911f*ax);
  float p=t*(0.254829592f+t*(-0.284496736f+t*(1.421413741f+t*(-1.453152027f+t*1.061405429f))));
  float er=1.0f - p*__expf(-ax*ax);
  er = (xs<0.f)? -er : er;
  return 0.5f*x*(1.0f+er);
}
// tanh-form GELU: x/(1+e^{x(c1+c2 x^2)}), |dev from erf-gelu|<=3e-4 (<< bf16 noise) - hot path
static __device__ __forceinline__ float gelu_t(float x){
  float x2=x*x;
  float y=x*(-1.5957691216f + x2*(-0.0713548162f));
  float e=__expf(y);
  return x*__builtin_amdgcn_rcpf(1.0f+e);
}
static __device__ __forceinline__ float ldin(const void* p, size_t i, int isbf){
  return isbf ? bf2f(((const unsigned short*)p)[i]) : ((const float*)p)[i];
}

static __device__ __forceinline__ void block_sum2(float a, float b, float&A, float&Bv, float* red, int nw){
  int lane=threadIdx.x&63, w=threadIdx.x>>6;
  #pragma unroll
  for(int o=32;o>0;o>>=1){ a+=__shfl_down(a,o); b+=__shfl_down(b,o); }
  if(lane==0){ red[w]=a; red[8+w]=b; }
  __syncthreads();
  float sa=0.f, sb=0.f;
  for(int i=0;i<nw;i++){ sa+=red[i]; sb+=red[8+i]; }
  __syncthreads();
  A=sa; Bv=sb;
}

// ---------------- fused sort (hist + scan + scatter) + dtype sniff ----------------
// blocks 0..31 (1024 thr, 16 waves): counting sort of graph g's edges by dst. block 32: sniff.
__global__ __launch_bounds__(1024) void sort_kernel(
  const int* __restrict__ src, const int* __restrict__ dst,
  int* __restrict__ rowptr, unsigned short* __restrict__ ss,
  const unsigned int* __restrict__ xw, int* __restrict__ flag)
{
  int t=threadIdx.x;
  if(blockIdx.x==32){
    if(t<64){
      int cnt=0;
      for(int i=0;i<32;i++){
        unsigned int w=xw[t+64*i];
        float v=bf2f((unsigned short)(w&0xffffu));
        float av=fabsf(v);
        if(v==0.0f || (av>=6e-5f && av<=8.0f)) cnt++;
      }
      #pragma unroll
      for(int o=32;o>0;o>>=1) cnt+=__shfl_down(cnt,o);
      if(t==0) *flag=(cnt>=1024)?1:0;
    }
    return;
  }
  __shared__ int cnts[512];
  __shared__ int offs[512];
  __shared__ int wred[8];
  int g=blockIdx.x;
  if(t<512) cnts[t]=0;
  __syncthreads();
  const int* dg=dst+(size_t)g*E_;
  #pragma unroll
  for(int e=t;e<E_;e+=1024) atomicAdd(&cnts[dg[e]],1);
  __syncthreads();
  // block exclusive scan over 512 counters: threads 0..255, thread t owns {2t, 2t+1}
  if(t<256){
    int lane=t&63, w=t>>6;
    int c0=cnts[2*t], c1=cnts[2*t+1];
    int mysum=c0+c1;
    int sc=mysum;
    #pragma unroll
    for(int o=1;o<64;o<<=1){ int v=__shfl_up(sc,o); if(lane>=o) sc+=v; }
    if(lane==63) wred[w]=sc;
    __syncthreads();
    int wbase=0;
    for(int i=0;i<w;i++) wbase+=wred[i];
    int excl=wbase+sc-mysum;
    rowptr[g*513+2*t  ]=excl;
    rowptr[g*513+2*t+1]=excl+c0;
    offs[2*t  ]=excl;
    offs[2*t+1]=excl+c0;
    if(t==255) rowptr[g*513+512]=wbase+sc;
  } else {
    __syncthreads();
  }
  __syncthreads();
  const int* sg=src+(size_t)g*E_;
  unsigned short* ssg=ss+(size_t)g*E_;
  #pragma unroll
  for(int e=t;e<E_;e+=1024){
    int d=dg[e];
    int pos=atomicAdd(&offs[d],1);
    ssg[pos]=(unsigned short)sg[e];
  }
}

// cb layout (bf16 canonical):
// [0,1152) qkv bias | [1152,1536) ob | [1536,1920) msg_b1 | [1920,2304) msg_b2
// [2304,2688) msg_g | [2688,3072) msg_bb | [3072,3456) attn_g | [3456,3840) attn_b
// [3840,4096) enc_b1 | [4096,4352) enc_g1 | [4352,4608) enc_bn1
// [4608,4736) enc_b2 | [4736,4864) enc_g2 | [4864,4992) enc_bn2
// [4992,5248) gh_b1 | [5248,5504) gh_g | [5504,5760) gh_bn | [5760,5776) gh_b2
__global__ __launch_bounds__(256) void prep_kernel(
  const void* __restrict__ msg_w1, const void* __restrict__ msg_w2,
  const void* __restrict__ qw, const void* __restrict__ kw,
  const void* __restrict__ vw, const void* __restrict__ ow,
  const void* __restrict__ qb, const void* __restrict__ kb, const void* __restrict__ vb,
  const void* __restrict__ ob, const void* __restrict__ msg_b1, const void* __restrict__ msg_b2,
  const void* __restrict__ msg_g, const void* __restrict__ msg_bb,
  const void* __restrict__ attn_g, const void* __restrict__ attn_b,
  const void* __restrict__ enc_w1, const void* __restrict__ enc_w2,
  const void* __restrict__ enc_b1, const void* __restrict__ enc_g1, const void* __restrict__ enc_bn1,
  const void* __restrict__ enc_b2, const void* __restrict__ enc_g2, const void* __restrict__ enc_bn2,
  const void* __restrict__ gh_w1, const void* __restrict__ gh_w2,
  const void* __restrict__ gh_b1, const void* __restrict__ gh_g,
  const void* __restrict__ gh_bn, const void* __restrict__ gh_b2,
  unsigned short* __restrict__ w1t, unsigned short* __restrict__ w2k,
  unsigned short* __restrict__ qkvt, unsigned short* __restrict__ owt,
  unsigned short* __restrict__ w1te, unsigned short* __restrict__ w2te,
  unsigned short* __restrict__ ghw1t, unsigned short* __restrict__ ghw2t,
  unsigned short* __restrict__ cb, const int* __restrict__ flag)
{
  int isbf=*flag;
  int job=blockIdx.y;
  int i=blockIdx.x*256+threadIdx.x;
  if(job<3){ // msg_w1[l] [256][128] -> [128][256] n-major
    if(i<32768){ int l=job; int k=i>>7, n=i&127; w1t[l*32768 + n*256 + k]=f2bf(ldin(msg_w1,(size_t)l*32768+i,isbf)); }
  } else if(job<6){ // msg_w2[l] straight copy [128k][128n]
    int l=job-3; if(i<16384){ w2k[l*16384 + i]=f2bf(ldin(msg_w2,(size_t)l*16384+i,isbf)); }
  } else if(job<15){
    int r=job-6, l=r/3, which=r%3;
    if(i<16384){ int k=i>>7, n=i&127;
      const void* w=(which==0)?qw:((which==1)?kw:vw);
      qkvt[l*49152 + (which*128+n)*128 + k]=f2bf(ldin(w,(size_t)l*16384+i,isbf)); }
  } else if(job<18){
    int l=job-15; if(i<16384){ int k=i>>7, n=i&127; owt[l*16384 + n*128 + k]=f2bf(ldin(ow,(size_t)l*16384+i,isbf)); }
  } else if(job==18){
    if(i<3840){
      float v;
      if(i<1152){ int l=i/384, j=i%384, which=j>>7, jj=j&127;
        const void* bb=(which==0)?qb:((which==1)?kb:vb);
        v=ldin(bb,(size_t)l*128+jj,isbf);
      } else {
        int i2=i-1152; int r=i2/384; int rem=i2%384;
        const void* s = (r==0)?ob:((r==1)?msg_b1:((r==2)?msg_b2:((r==3)?msg_g:((r==4)?msg_bb:((r==5)?attn_g:attn_b)))));
        v=ldin(s,(size_t)rem,isbf);
      }
      cb[i]=f2bf(v);
    }
  } else if(job==19){
    if(i<1152){
      float v;
      if(i<256)       v=ldin(enc_b1,i,isbf);
      else if(i<512)  v=ldin(enc_g1,i-256,isbf);
      else if(i<768)  v=ldin(enc_bn1,i-512,isbf);
      else if(i<896)  v=ldin(enc_b2,i-768,isbf);
      else if(i<1024) v=ldin(enc_g2,i-896,isbf);
      else            v=ldin(enc_bn2,i-1024,isbf);
      cb[3840+i]=f2bf(v);
    }
  } else if(job==20){
    if(i<16384){ int k=i>>8, n=i&255; w1te[n*64+k]=f2bf(ldin(enc_w1,(size_t)i,isbf)); }
  } else if(job==21){
    if(i<32768){ int k=i>>7, n=i&127; w2te[n*256+k]=f2bf(ldin(enc_w2,(size_t)i,isbf)); }
  } else if(job<26){
    int p=job-22; int j=p*32768+i;
    if(i<32768){ int k=j>>8, n=j&255; ghw1t[n*512+k]=f2bf(ldin(gh_w1,(size_t)j,isbf)); }
  } else {
    if(i<2560){ int k=i/10, n=i%10; ghw2t[n*256+k]=f2bf(ldin(gh_w2,(size_t)i,isbf)); }
    else if(i<2560+778){
      int j=i-2560; float v;
      if(j<256)      v=ldin(gh_b1,j,isbf);
      else if(j<512) v=ldin(gh_g,j-256,isbf);
      else if(j<768) v=ldin(gh_bn,j-512,isbf);
      else           v=ldin(gh_b2,j-768,isbf);
      cb[4992+j]=f2bf(v);
    }
  }
}

// ---------------- fused node encoder (+ layer-0 UV generation) ----------------
__global__ __launch_bounds__(256) void enc_kernel(
  const void* __restrict__ x, const unsigned short* __restrict__ w1te,
  const unsigned short* __restrict__ w2te, const unsigned short* __restrict__ cb,
  unsigned short* __restrict__ h, const int* __restrict__ flag,
  const unsigned short* __restrict__ w1t0, unsigned short* __restrict__ UV)
{
  __shared__ __align__(16) unsigned short xs[64][72];
  __shared__ __align__(16) unsigned short t1[64][264];
  int isbf=*flag;
  int m0=blockIdx.x*64;
  int t=threadIdx.x, lane=t&63, w=t>>6, quad=lane>>4, ln=lane&15;
  for(int c2=t;c2<1024;c2+=256){
    int i=c2*4, row=i>>6, col=i&63;
    float v0,v1,v2,v3;
    if(isbf){
      const unsigned short* p=(const unsigned short*)x+(size_t)m0*64+i;
      v0=bf2f(p[0]); v1=bf2f(p[1]); v2=bf2f(p[2]); v3=bf2f(p[3]);
    } else {
      float4 f=*(const float4*)((const float*)x+(size_t)m0*64+i);
      v0=f.x; v1=f.y; v2=f.z; v3=f.w;
    }
    ushort4 o; o.x=f2bf(v0); o.y=f2bf(v1); o.z=f2bf(v2); o.w=f2bf(v3);
    *(ushort4*)&xs[row][col]=o;
  }
  __syncthreads();
  f32x4 a[4][4];
  #pragma unroll
  for(int nt=0;nt<4;nt++){ a[nt][0]={0,0,0,0}; a[nt][1]={0,0,0,0}; a[nt][2]={0,0,0,0}; a[nt][3]={0,0,0,0}; }
  #pragma unroll
  for(int k0i=0;k0i<2;k0i++){
    bf16x8 af[4];
    #pragma unroll
    for(int f=0;f<4;f++) af[f]=*(const bf16x8*)(&xs[f*16+ln][k0i*32+quad*8]);
    #pragma unroll
    for(int nt=0;nt<4;nt++){
      int n=w*64+nt*16+ln;
      bf16x8 bfr=*(const bf16x8*)(w1te+(size_t)n*64+k0i*32+quad*8);
      #pragma unroll
      for(int f=0;f<4;f++) a[nt][f]=__builtin_amdgcn_mfma_f32_16x16x32_bf16(af[f],bfr,a[nt][f],0,0,0);
    }
  }
  #pragma unroll
  for(int nt=0;nt<4;nt++){
    int n=w*64+nt*16+ln;
    float bv=bf2f(cb[3840+n]);
    #pragma unroll
    for(int f=0;f<4;f++)
      #pragma unroll
      for(int r=0;r<4;r++) t1[f*16+quad*4+r][n]=f2bf(a[nt][f][r]+bv);
  }
  __syncthreads();
  {
    int row=t>>2, qq=t&3;
    float s=0.f,s2=0.f;
    for(int c=qq*64;c<qq*64+64;c++){ float v=bf2f(t1[row][c]); s+=v; s2+=v*v; }
    s+=__shfl_xor(s,1); s+=__shfl_xor(s,2);
    s2+=__shfl_xor(s2,1); s2+=__shfl_xor(s2,2);
    float mu=s*(1.f/256.f), var=fmaxf(s2*(1.f/256.f)-mu*mu,0.f);
    float rr=rsqrtf(var+1e-5f);
    for(int c=qq*64;c<qq*64+64;c++){
      float v=bf2f(t1[row][c]);
      t1[row][c]=f2bf(gelu_f((v-mu)*rr*bf2f(cb[4096+c])+bf2f(cb[4352+c])));
    }
  }
  __syncthreads();
  f32x4 b2a[2][4];
  #pragma unroll
  for(int nt=0;nt<2;nt++){ b2a[nt][0]={0,0,0,0}; b2a[nt][1]={0,0,0,0}; b2a[nt][2]={0,0,0,0}; b2a[nt][3]={0,0,0,0}; }
  #pragma unroll
  for(int k0i=0;k0i<8;k0i++){
    bf16x8 af[4];
    #pragma unroll
    for(int f=0;f<4;f++) af[f]=*(const bf16x8*)(&t1[f*16+ln][k0i*32+quad*8]);
    #pragma unroll
    for(int nt=0;nt<2;nt++){
      int n=w*32+nt*16+ln;
      bf16x8 bfr=*(const bf16x8*)(w2te+(size_t)n*256+k0i*32+quad*8);
      #pragma unroll
      for(int f=0;f<4;f++) b2a[nt][f]=__builtin_amdgcn_mfma_f32_16x16x32_bf16(af[f],bfr,b2a[nt][f],0,0,0);
    }
  }
  __syncthreads();
  float* mf=(float*)&t1[0][0];   // [64][132]
  #pragma unroll
  for(int nt=0;nt<2;nt++){
    int n=w*32+nt*16+ln;
    float bv=bf2f(cb[4608+n]);
    #pragma unroll
    for(int f=0;f<4;f++)
      #pragma unroll
      for(int r=0;r<4;r++) mf[(f*16+quad*4+r)*132+n]=b2a[nt][f][r]+bv;
  }
  __syncthreads();
  {
    int row=t>>2, qq=t&3;
    float vals[32];
    float s=0.f,s2=0.f;
    for(int j=0;j<32;j++){ float v=mf[row*132+qq*32+j]; vals[j]=v; s+=v; s2+=v*v; }
    s+=__shfl_xor(s,1); s+=__shfl_xor(s,2);
    s2+=__shfl_xor(s2,1); s2+=__shfl_xor(s2,2);
    float mu=s*(1.f/128.f), var=fmaxf(s2*(1.f/128.f)-mu*mu,0.f);
    float rr=rsqrtf(var+1e-5f);
    for(int j=0;j<32;j+=2){
      int c=qq*32+j;
      float v0=(vals[j]  -mu)*rr*bf2f(cb[4736+c  ])+bf2f(cb[4864+c  ]);
      float v1=(vals[j+1]-mu)*rr*bf2f(cb[4736+c+1])+bf2f(cb[4864+c+1]);
      *(unsigned int*)(h+(size_t)(m0+row)*128+c)=pack2(v0,v1);
      vals[j]=v0; vals[j+1]=v1;
    }
    __syncthreads();   // all mf reads done before t1 reuse as hb
    unsigned short* hb=&t1[0][0];  // [64][136] bf16
    for(int j=0;j<32;j++) hb[row*136+qq*32+j]=f2bf(vals[j]);
  }
  __syncthreads();
  // ---- fused uvgen for layer 0: UV[m0..m0+64) = [h@W1a+b1 | h@W1b] ----
  {
    const unsigned short* hb=&t1[0][0];
    #pragma unroll
    for(int y=0;y<2;y++)
    #pragma unroll
    for(int nt=0;nt<2;nt++){
      int n=w*32+nt*16+ln;
      f32x4 a0={0,0,0,0},a1={0,0,0,0},a2={0,0,0,0},a3={0,0,0,0};
      const unsigned short* wp=w1t0+(size_t)n*256+y*128+quad*8;
      #pragma unroll
      for(int k0=0;k0<128;k0+=32){
        bf16x8 bfr=*(const bf16x8*)(wp+k0);
        bf16x8 f0=*(const bf16x8*)(hb+(size_t)(ln   )*136+k0+quad*8);
        bf16x8 f1=*(const bf16x8*)(hb+(size_t)(16+ln)*136+k0+quad*8);
        bf16x8 f2=*(const bf16x8*)(hb+(size_t)(32+ln)*136+k0+quad*8);
        bf16x8 f3=*(const bf16x8*)(hb+(size_t)(48+ln)*136+k0+quad*8);
        a0=__builtin_amdgcn_mfma_f32_16x16x32_bf16(f0,bfr,a0,0,0,0);
        a1=__builtin_amdgcn_mfma_f32_16x16x32_bf16(f1,bfr,a1,0,0,0);
        a2=__builtin_amdgcn_mfma_f32_16x16x32_bf16(f2,bfr,a2,0,0,0);
        a3=__builtin_amdgcn_mfma_f32_16x16x32_bf16(f3,bfr,a3,0,0,0);
      }
      float bv=y?0.f:bf2f(cb[1536+n]);
      #pragma unroll
      for(int r=0;r<4;r++){
        UV[(size_t)(m0   +quad*4+r)*256+y*128+n]=f2bf(a0[r]+bv);
        UV[(size_t)(m0+16+quad*4+r)*256+y*128+n]=f2bf(a1[r]+bv);
        UV[(size_t)(m0+32+quad*4+r)*256+y*128+n]=f2bf(a2[r]+bv);
        UV[(size_t)(m0+48+quad*4+r)*256+y*128+n]=f2bf(a3[r]+bv);
      }
    }
  }
}

// ---------------- QKV generation: Q (pre-scaled, row-major), K (row-major), V^T ----------------
// grid (gA*8, 3): y=0 -> Q, y=1 -> K, y=2 -> V written transposed [g][128 dims][512 keys]
__global__ __launch_bounds__(256) void qkvgen_kernel(
  const unsigned short* __restrict__ hrows, const unsigned short* __restrict__ wqkv,
  const unsigned short* __restrict__ bqkv,
  unsigned short* __restrict__ Qb, unsigned short* __restrict__ Kb,
  unsigned short* __restrict__ Vtb)
{
  __shared__ __align__(16) unsigned short a_t[64][136];
  int t=threadIdx.x;
  int m0=blockIdx.x*64;
  int y=blockIdx.y;
  for(int c=t;c<1024;c+=256){
    int m=c>>4, pp=c&15;
    *(uint4*)&a_t[m][pp*8]=*((const uint4*)(hrows+(size_t)(m0+m)*128)+pp);
  }
  __syncthreads();
  int lane=t&63, w=t>>6, quad=lane>>4, ln=lane&15;
  int gloc=m0>>9, r0=m0&511;
  #pragma unroll
  for(int nt=0;nt<2;nt++){
    int n=w*32+nt*16+ln;
    f32x4 a0={0,0,0,0},a1={0,0,0,0},a2={0,0,0,0},a3={0,0,0,0};
    const unsigned short* wp=wqkv+(size_t)(y*128+n)*128+quad*8;
    #pragma unroll
    for(int k0=0;k0<128;k0+=32){
      bf16x8 bfr=*(const bf16x8*)(wp+k0);
      bf16x8 f0=*(const bf16x8*)(&a_t[ln   ][k0+quad*8]);
      bf16x8 f1=*(const bf16x8*)(&a_t[16+ln][k0+quad*8]);
      bf16x8 f2=*(const bf16x8*)(&a_t[32+ln][k0+quad*8]);
      bf16x8 f3=*(const bf16x8*)(&a_t[48+ln][k0+quad*8]);
      a0=__builtin_amdgcn_mfma_f32_16x16x32_bf16(f0,bfr,a0,0,0,0);
      a1=__builtin_amdgcn_mfma_f32_16x16x32_bf16(f1,bfr,a1,0,0,0);
      a2=__builtin_amdgcn_mfma_f32_16x16x32_bf16(f2,bfr,a2,0,0,0);
      a3=__builtin_amdgcn_mfma_f32_16x16x32_bf16(f3,bfr,a3,0,0,0);
    }
    float bv=bf2f(bqkv[y*128+n]);
    if(y==0){
      const float sc=0.17677669529663689f;
      #pragma unroll
      for(int r=0;r<4;r++){
        Qb[(size_t)(m0   +quad*4+r)*128+n]=f2bf((a0[r]+bv)*sc);
        Qb[(size_t)(m0+16+quad*4+r)*128+n]=f2bf((a1[r]+bv)*sc);
        Qb[(size_t)(m0+32+quad*4+r)*128+n]=f2bf((a2[r]+bv)*sc);
        Qb[(size_t)(m0+48+quad*4+r)*128+n]=f2bf((a3[r]+bv)*sc);
      }
    } else if(y==1){
      #pragma unroll
      for(int r=0;r<4;r++){
        Kb[(size_t)(m0   +quad*4+r)*128+n]=f2bf(a0[r]+bv);
        Kb[(size_t)(m0+16+quad*4+r)*128+n]=f2bf(a1[r]+bv);
        Kb[(size_t)(m0+32+quad*4+r)*128+n]=f2bf(a2[r]+bv);
        Kb[(size_t)(m0+48+quad*4+r)*128+n]=f2bf(a3[r]+bv);
      }
    } else {
      unsigned short* vrow = Vtb + ((size_t)gloc*128+n)*512 + r0 + quad*4;
      ushort4 o;
      o.x=f2bf(a0[0]+bv); o.y=f2bf(a0[1]+bv); o.z=f2bf(a0[2]+bv); o.w=f2bf(a0[3]+bv);
      *(ushort4*)(vrow)=o;
      o.x=f2bf(a1[0]+bv); o.y=f2bf(a1[1]+bv); o.z=f2bf(a1[2]+bv); o.w=f2bf(a1[3]+bv);
      *(ushort4*)(vrow+16)=o;
      o.x=f2bf(a2[0]+bv); o.y=f2bf(a2[1]+bv); o.z=f2bf(a2[2]+bv); o.w=f2bf(a2[3]+bv);
      *(ushort4*)(vrow+32)=o;
      o.x=f2bf(a3[0]+bv); o.y=f2bf(a3[1]+bv); o.z=f2bf(a3[2]+bv); o.w=f2bf(a3[3]+bv);
      *(ushort4*)(vrow+48)=o;
    }
  }
}

// ---------------- fused edge phase: branchless gather (fast gelu) + k-split GEMV ----------------
__global__ __launch_bounds__(128) void edgef_kernel(
  unsigned short* __restrict__ h,
  const unsigned short* __restrict__ UV,      // full rows [B*512][256], global-g indexed
  const unsigned short* __restrict__ ss,
  const int* __restrict__ rowptr,
  const unsigned short* __restrict__ w2k,     // [128k][128n]
  const unsigned short* __restrict__ b2,
  const unsigned short* __restrict__ gg, const unsigned short* __restrict__ bbp,
  int b0, int gEp)
{
  __shared__ __align__(16) float aggL[2][4][128];
  __shared__ __align__(16) float po[2][4][128];
  int t=threadIdx.x, lane=t&63, w=t>>6;
  int bid=blockIdx.x;
  int lg=bid%gEp, ch=bid/gEp;     // ch in [0,128): 4-dst chunk
  int g=b0+lg;
  const unsigned short* UVg = UV + (size_t)g*512*256;
  const unsigned short* ssg = ss + (size_t)g*E_;
  int dbase = ch*4;
  int bnd[5];
  #pragma unroll
  for(int i=0;i<5;i++) bnd[i]=rowptr[g*513+dbase+i];
  // ---- gather: wave w takes its half of each dst's edge range (branchless, masked idx) ----
  #pragma unroll 1
  for(int dd=0;dd<4;dd++){
    int e_lo=bnd[dd], e_hi0=bnd[dd+1];
    int half=(e_hi0-e_lo+1)>>1;
    int es = w ? (e_lo+half) : e_lo;
    int ee = w ? e_hi0       : (e_lo+half);
    unsigned int vdw=*(const unsigned int*)(UVg + (size_t)(dbase+dd)*256 + 128 + lane*2);
    float v0=bf2f((unsigned short)(vdw&0xffffu)), v1=bf2f((unsigned short)(vdw>>16));
    float a0=0.f, a1=0.f;
    int si3,si4,si5;
    unsigned int u0,u1,u2;
    {
      // over-reads (<=6 u16 past range) stay in-ws; idx masked &511
      int s0=__builtin_amdgcn_readfirstlane((int)ssg[es  ])&511;
      int s1=__builtin_amdgcn_readfirstlane((int)ssg[es+1])&511;
      int s2=__builtin_amdgcn_readfirstlane((int)ssg[es+2])&511;
      si3=(int)ssg[es+3]; si4=(int)ssg[es+4]; si5=(int)ssg[es+5];
      u0=*(const unsigned int*)(UVg + (size_t)s0*256 + lane*2);
      u1=*(const unsigned int*)(UVg + (size_t)s1*256 + lane*2);
      u2=*(const unsigned int*)(UVg + (size_t)s2*256 + lane*2);
    }
    #pragma unroll 2
    for(int e=es;e<ee;e++){
      float z0=bf2f((unsigned short)(u0&0xffffu))+v0;
      float z1=bf2f((unsigned short)(u0>>16))+v1;
      u0=u1; u1=u2;
      int s3=__builtin_amdgcn_readfirstlane(si3)&511;
      u2=*(const unsigned int*)(UVg + (size_t)s3*256 + lane*2);
      si3=si4; si4=si5;
      si5=(int)ssg[e+6];
      a0+=gelu_t(z0); a1+=gelu_t(z1);
    }
    aggL[w][dd][lane*2  ]=a0;
    aggL[w][dd][lane*2+1]=a1;
  }
  __syncthreads();
  // ---- GEMV k-split: wave w does all 4 dst over k in [w*64, w*64+64) ----
  float o[4][2];
  #pragma unroll
  for(int dd=0;dd<4;dd++){ o[dd][0]=0.f; o[dd][1]=0.f; }
  #pragma unroll 4
  for(int kk=0;kk<64;kk++){
    int k=w*64+kk;
    unsigned int wdw=*(const unsigned int*)(w2k+(size_t)k*128+lane*2);
    float w0=bf2f((unsigned short)(wdw&0xffffu));
    float w1=bf2f((unsigned short)(wdw>>16));
    #pragma unroll
    for(int dd=0;dd<4;dd++){
      float av=aggL[0][dd][k]+aggL[1][dd][k];
      o[dd][0]+=av*w0; o[dd][1]+=av*w1;
    }
  }
  #pragma unroll
  for(int dd=0;dd<4;dd++){
    po[w][dd][lane*2  ]=o[dd][0];
    po[w][dd][lane*2+1]=o[dd][1];
  }
  __syncthreads();
  // ---- combine partials + deg*b2 + residual + LN: wave w owns dst pair {2w, 2w+1} ----
  #pragma unroll 1
  for(int p=0;p<2;p++){
    int di=w*2+p;
    int d = dbase + di;
    float deg=(float)(bnd[di+1]-bnd[di]);
    float o0=bf2f(b2[lane*2  ])*deg + po[0][di][lane*2  ] + po[1][di][lane*2  ];
    float o1=bf2f(b2[lane*2+1])*deg + po[0][di][lane*2+1] + po[1][di][lane*2+1];
    size_t base=(size_t)(g*512+d)*128;
    unsigned int hdw=*(const unsigned int*)(h+base+lane*2);
    float x0=bf2f((unsigned short)(hdw&0xffffu))+o0;
    float x1=bf2f((unsigned short)(hdw>>16))+o1;
    float s1=x0+x1, s2=x0*x0+x1*x1;
    #pragma unroll
    for(int off=32;off>0;off>>=1){ s1+=__shfl_xor(s1,off); s2+=__shfl_xor(s2,off); }
    float mu=s1*(1.f/128.f), var=fmaxf(s2*(1.f/128.f)-mu*mu,0.f);
    float rr=rsqrtf(var+1e-5f);
    float y0=(x0-mu)*rr*bf2f(gg[lane*2  ])+bf2f(bbp[lane*2  ]);
    float y1=(x1-mu)*rr*bf2f(gg[lane*2+1])+bf2f(bbp[lane*2+1]);
    *(unsigned int*)(h+base+lane*2)=pack2(y0,y1);
  }
}

// ---------------- fused flash attention + oproj + residual/LN + next-layer uvgen / pool partials ----------------
// grid gA*16: block = (graph lg, 32-row tile ch). wave w = head w. barrier-free flash.
// Psh double-buffered by qt-parity. s_setprio(1) wraps the MFMA clusters (T5: waves progress at
// independent phases in the barrier-free loop, so prioritizing MFMA-entering waves pays).
__global__ __launch_bounds__(256) void attn_fused_kernel(
  const unsigned short* __restrict__ Qb, const unsigned short* __restrict__ Kb,
  const unsigned short* __restrict__ Vtb,
  const unsigned short* __restrict__ wo, const unsigned short* __restrict__ bo,
  unsigned short* __restrict__ h,
  const unsigned short* __restrict__ gg, const unsigned short* __restrict__ bbp,
  const unsigned short* __restrict__ w1tn, const unsigned short* __restrict__ b1n,
  unsigned short* __restrict__ UV, float* part, int b0, int gA, int do_uv)
{
  __shared__ __align__(16) unsigned short hO[32][136];
  __shared__ __align__(16) unsigned short Psh[2][4][16][72];
  __shared__ __align__(16) float mf[32][132];
  int bx=blockIdx.x;
  int lg=bx%gA, ch=bx/gA;           // ch in [0,16)
  int r0=ch*32;
  int g=b0+lg;
  int t=threadIdx.x, lane=t&63, w=t>>6, quad=lane>>4, ln=lane&15;
  const unsigned short* Qg = Qb + (size_t)lg*65536;
  const unsigned short* Kg = Kb + (size_t)lg*65536 + w*32;
  const unsigned short* Vg = Vtb + ((size_t)lg*128 + w*32)*512;
  // ---- flash: wave w = head w, rows [r0, r0+32) ----
  bf16x8 qf[2];
  #pragma unroll
  for(int qt=0;qt<2;qt++)
    qf[qt]=*(const bf16x8*)(Qg + (size_t)(r0+qt*16+ln)*128 + w*32 + quad*8);
  f32x4 O[2][2]; float Lp[2][4];
  #pragma unroll
  for(int qt=0;qt<2;qt++){ O[qt][0]={0,0,0,0}; O[qt][1]={0,0,0,0};
    #pragma unroll
    for(int r=0;r<4;r++) Lp[qt][r]=0.f; }
  for(int kc=0;kc<8;kc++){
    bf16x8 kf[4];
    #pragma unroll
    for(int f=0;f<4;f++) kf[f]=*(const bf16x8*)(Kg + (size_t)(kc*64+f*16+ln)*128 + quad*8);
    bf16x8 va[2], vb[2];
    #pragma unroll
    for(int s2=0;s2<2;s2++){
      va[s2]=*(const bf16x8*)(Vg + (size_t)ln*512      + kc*64 + s2*32 + quad*8);
      vb[s2]=*(const bf16x8*)(Vg + (size_t)(16+ln)*512 + kc*64 + s2*32 + quad*8);
    }
    #pragma unroll
    for(int qt=0;qt<2;qt++){
      f32x4 s[4];
      __builtin_amdgcn_s_setprio(1);
      #pragma unroll
      for(int f=0;f<4;f++){
        f32x4 z={0,0,0,0};
        s[f]=__builtin_amdgcn_mfma_f32_16x16x32_bf16(qf[qt],kf[f],z,0,0,0);
      }
      __builtin_amdgcn_s_setprio(0);
      #pragma unroll
      for(int f=0;f<4;f++)
        #pragma unroll
        for(int r=0;r<4;r++){
          float pe=__expf(fminf(s[f][r],30.0f));
          Psh[qt][w][quad*4+r][f*16+ln]=f2bf(pe);
          Lp[qt][r]+=pe;
        }
      __builtin_amdgcn_s_setprio(1);
      #pragma unroll
      for(int s2=0;s2<2;s2++){
        bf16x8 pf=*(const bf16x8*)(&Psh[qt][w][ln][s2*32+quad*8]);
        O[qt][0]=__builtin_amdgcn_mfma_f32_16x16x32_bf16(pf,va[s2],O[qt][0],0,0,0);
        O[qt][1]=__builtin_amdgcn_mfma_f32_16x16x32_bf16(pf,vb[s2],O[qt][1],0,0,0);
      }
      __builtin_amdgcn_s_setprio(0);
    }
  }
  #pragma unroll
  for(int qt=0;qt<2;qt++){
    #pragma unroll
    for(int o=1;o<16;o<<=1)
      #pragma unroll
      for(int r=0;r<4;r++) Lp[qt][r]+=__shfl_xor(Lp[qt][r],o);
    #pragma unroll
    for(int r=0;r<4;r++){
      float inv=1.0f/Lp[qt][r];
      int qr=qt*16+quad*4+r;
      hO[qr][w*32+ln   ]=f2bf(O[qt][0][r]*inv);
      hO[qr][w*32+16+ln]=f2bf(O[qt][1][r]*inv);
    }
  }
  __syncthreads();
  // ---- oproj GEMM on the 32-row tile ----
  #pragma unroll
  for(int nt=0;nt<2;nt++){
    int n=w*32+nt*16+ln;
    f32x4 a0={0,0,0,0},a1={0,0,0,0};
    const unsigned short* wp=wo+(size_t)n*128+quad*8;
    #pragma unroll
    for(int k0=0;k0<128;k0+=32){
      bf16x8 bfr=*(const bf16x8*)(wp+k0);
      bf16x8 f0=*(const bf16x8*)(&hO[ln   ][k0+quad*8]);
      bf16x8 f1=*(const bf16x8*)(&hO[16+ln][k0+quad*8]);
      a0=__builtin_amdgcn_mfma_f32_16x16x32_bf16(f0,bfr,a0,0,0,0);
      a1=__builtin_amdgcn_mfma_f32_16x16x32_bf16(f1,bfr,a1,0,0,0);
    }
    float bv=bf2f(bo[n]);
    #pragma unroll
    for(int r=0;r<4;r++){
      mf[quad*4+r   ][n]=a0[r]+bv;
      mf[16+quad*4+r][n]=a1[r]+bv;
    }
  }
  __syncthreads();
  // ---- residual + LN; write h, refill hO (bf16) and mf (f32) with new-h ----
  {
    int row=t>>3, oct=t&7;
    size_t base=((size_t)(g*512+r0+row))*128;
    float vals[16];
    float s=0.f,s2=0.f;
    for(int j=0;j<16;j++){
      int c=oct*16+j;
      float v=bf2f(h[base+c])+mf[row][c];
      vals[j]=v; s+=v; s2+=v*v;
    }
    s+=__shfl_xor(s,1); s+=__shfl_xor(s,2); s+=__shfl_xor(s,4);
    s2+=__shfl_xor(s2,1); s2+=__shfl_xor(s2,2); s2+=__shfl_xor(s2,4);
    float mu=s*(1.f/128.f), var=fmaxf(s2*(1.f/128.f)-mu*mu,0.f);
    float rr=rsqrtf(var+1e-5f);
    for(int j=0;j<16;j+=2){
      int c=oct*16+j;
      float y0=(vals[j]  -mu)*rr*bf2f(gg[c  ])+bf2f(bbp[c  ]);
      float y1=(vals[j+1]-mu)*rr*bf2f(gg[c+1])+bf2f(bbp[c+1]);
      *(unsigned int*)(h+base+c)=pack2(y0,y1);
      hO[row][c]=f2bf(y0); hO[row][c+1]=f2bf(y1);
      mf[row][c]=y0; mf[row][c+1]=y1;
    }
  }
  __syncthreads();
  if(!do_uv){
    // ---- pool partials for this 32-row tile ----
    if(t<128){
      float s=0.f,s2=0.f,mx=-1e30f;
      for(int r=0;r<32;r++){ float v=mf[r][t]; s+=v; s2+=v*v; mx=fmaxf(mx,v); }
      size_t pb=((size_t)(g*16+ch))*384;
      part[pb+t]=s; part[pb+128+t]=s2; part[pb+256+t]=mx;
    }
    return;
  }
  // ---- next-layer uvgen on the 32-row tile ----
  #pragma unroll
  for(int y=0;y<2;y++)
  #pragma unroll
  for(int nt=0;nt<2;nt++){
    int n=w*32+nt*16+ln;
    f32x4 a0={0,0,0,0},a1={0,0,0,0};
    const unsigned short* wp=w1tn+(size_t)n*256+y*128+quad*8;
    #pragma unroll
    for(int k0=0;k0<128;k0+=32){
      bf16x8 bfr=*(const bf16x8*)(wp+k0);
      bf16x8 f0=*(const bf16x8*)(&hO[ln   ][k0+quad*8]);
      bf16x8 f1=*(const bf16x8*)(&hO[16+ln][k0+quad*8]);
      a0=__builtin_amdgcn_mfma_f32_16x16x32_bf16(f0,bfr,a0,0,0,0);
      a1=__builtin_amdgcn_mfma_f32_16x16x32_bf16(f1,bfr,a1,0,0,0);
    }
    float bv=y?0.f:bf2f(b1n[n]);
    size_t rb=(size_t)(g*512+r0);
    #pragma unroll
    for(int r=0;r<4;r++){
      UV[(rb   +quad*4+r)*256+y*128+n]=f2bf(a0[r]+bv);
      UV[(rb+16+quad*4+r)*256+y*128+n]=f2bf(a1[r]+bv);
    }
  }
}

// ---------------- graph head: finalize pooling + MLP ----------------
__global__ __launch_bounds__(256) void head_kernel(
  const float* __restrict__ part, const unsigned short* __restrict__ ghw1t,
  const unsigned short* __restrict__ ghw2t, const unsigned short* __restrict__ cb,
  void* __restrict__ out, const int* __restrict__ flag)
{
  int isbf=*flag;
  int b=blockIdx.x, t=threadIdx.x;
  __shared__ float pl[512];
  __shared__ float gl[256];
  __shared__ float red[16];
  if(t<128){
    float s=0.f,s2=0.f,mx=-1e30f;
    for(int c=0;c<16;c++){
      size_t base=((size_t)(b*16+c))*384;
      s += part[base+t];
      s2+= part[base+128+t];
      mx = fmaxf(mx, part[base+256+t]);
    }
    float mean=s*(1.f/512.f);
    float var=fmaxf(s2*(1.f/512.f)-mean*mean,0.f);
    float sd=sqrtf(var+1e-6f);
    pl[t]=mean; pl[128+t]=s; pl[256+t]=mx; pl[384+t]=sd;
  }
  __syncthreads();
  float a=bf2f(cb[4992+t]);
  const unsigned short* wr=ghw1t+(size_t)t*512;
  for(int k0=0;k0<512;k0+=8){
    bf16x8 wv=*(const bf16x8*)(wr+k0);
    const unsigned short* wp=(const unsigned short*)&wv;
    #pragma unroll
    for(int j=0;j<8;j++) a+=pl[k0+j]*bf2f(wp[j]);
  }
  float u=gelu_f(a);
  float S,S2; block_sum2(u,u*u,S,S2,red,4);
  float mu=S*(1.f/256.f), var=fmaxf(S2*(1.f/256.f)-mu*mu,0.f);
  float r=rsqrtf(var+1e-5f);
  gl[t]=(u-mu)*r*bf2f(cb[5248+t])+bf2f(cb[5504+t]);
  __syncthreads();
  if(t<10){
    float o=bf2f(cb[5760+t]);
    const unsigned short* wr2=ghw2t+(size_t)t*256;
    for(int k0=0;k0<256;k0+=8){
      bf16x8 wv=*(const bf16x8*)(wr2+k0);
      const unsigned short* wp=(const unsigned short*)&wv;
      #pragma unroll
      for(int j=0;j<8;j++) o+=gl[k0+j]*bf2f(wp[j]);
    }
    if(isbf) ((unsigned short*)out)[b*10+t]=f2bf(o);
    else     ((float*)out)[b*10+t]=o;
  }
}

extern "C" void kernel_launch(void* const* d_in, const int* in_sizes, int n_in,
                              void* d_out, int out_size, void* d_ws, size_t ws_size,
                              hipStream_t stream)
{
  const void* x      =d_in[0];
  const int*  src    =(const int*)d_in[1];
  const int*  dstp   =(const int*)d_in[2];
  const void* enc_w1 =d_in[3];  const void* enc_b1 =d_in[4];
  const void* enc_g1 =d_in[5];  const void* enc_bn1=d_in[6];
  const void* enc_w2 =d_in[7];  const void* enc_b2 =d_in[8];
  const void* enc_g2 =d_in[9];  const void* enc_bn2=d_in[10];
  const void* msg_w1 =d_in[11]; const void* msg_b1 =d_in[12];
  const void* msg_w2 =d_in[13]; const void* msg_b2 =d_in[14];
  const void* msg_g  =d_in[15]; const void* msg_bb =d_in[16];
  const void* qw     =d_in[17]; const void* qb     =d_in[18];
  const void* kw     =d_in[19]; const void* kb     =d_in[20];
  const void* vw     =d_in[21]; const void* vb     =d_in[22];
  const void* ow     =d_in[23]; const void* ob     =d_in[24];
  const void* attn_g =d_in[25]; const void* attn_b =d_in[26];
  const void* gh_w1  =d_in[27]; const void* gh_b1  =d_in[28];
  const void* gh_g   =d_in[29]; const void* gh_bn  =d_in[30];
  const void* gh_w2  =d_in[31]; const void* gh_b2  =d_in[32];
  (void)in_sizes; (void)n_in; (void)out_size;

  char* base=(char*)d_ws;
  unsigned short* h    =(unsigned short*)(base);                 // 4 MB
  unsigned short* w1t  =(unsigned short*)(base + 4194304);
  unsigned short* w2k  =(unsigned short*)(base + 4390912);
  unsigned short* qkvt =(unsigned short*)(base + 4489216);
  unsigned short* owt  =(unsigned short*)(base + 4784128);
  unsigned short* w1te =(unsigned short*)(base + 4882432);
  unsigned short* w2te =(unsigned short*)(base + 4915200);
  unsigned short* ghw1t=(unsigned short*)(base + 4980736);
  unsigned short* ghw2t=(unsigned short*)(base + 5242880);
  unsigned short* cb   =(unsigned short*)(base + 5248000);
  int*   rowptr        =(int*)(base + 5325312);                  // 65664 B
  int*   flag          =(int*)(base + 5390976);
  unsigned short* ssrt =(unsigned short*)(base + 5505024);       // 512 KB (+edgef over-reads land in R)
  char* R              = base + 6029312;                          // shared region

  // R layout: UV (full, 8 MB) | Qb | Kb | Vtb  (per attn pass, gA graphs each)
  size_t Rcap = (ws_size > 6029312) ? (ws_size - 6029312) : 0;
  int gA = 32;
  while(gA > 4 && 8388608 + (size_t)gA*393216 > Rcap) gA >>= 1;
  int apass = 32/gA;
  unsigned short* UV  =(unsigned short*)R;                  // 16384 x 256 bf16 = 8 MB
  unsigned short* Qb  =UV  + 4194304;                       // gA*512*128 bf16
  unsigned short* Kb  =Qb  + (size_t)gA*65536;
  unsigned short* Vtb =Kb  + (size_t)gA*65536;
  float* part=(float*)R;   // pool partials: 32*16*384*4 = 786 KB (UV region free during l==2 attn)

  sort_kernel<<<33,1024,0,stream>>>(src,dstp,rowptr,ssrt,(const unsigned int*)x,flag);
  prep_kernel<<<dim3(128,27),256,0,stream>>>(msg_w1,msg_w2,qw,kw,vw,ow,qb,kb,vb,
      ob,msg_b1,msg_b2,msg_g,msg_bb,attn_g,attn_b,
      enc_w1,enc_w2,enc_b1,enc_g1,enc_bn1,enc_b2,enc_g2,enc_bn2,
      gh_w1,gh_w2,gh_b1,gh_g,gh_bn,gh_b2,
      w1t,w2k,qkvt,owt,w1te,w2te,ghw1t,ghw2t,cb,flag);

  enc_kernel<<<BN_/64,256,0,stream>>>(x,w1te,w2te,cb,h,flag,w1t,UV);

  for(int l=0;l<3;l++){
    edgef_kernel<<<32*128,128,0,stream>>>(h,UV,ssrt,rowptr,
        w2k+(size_t)l*16384, cb+1920+l*128, cb+2304+l*128, cb+2688+l*128, 0, 32);
    int ln=(l+1)%3;
    for(int ap=0;ap<apass;ap++){
      int b0=ap*gA;
      qkvgen_kernel<<<dim3(gA*8,3),256,0,stream>>>(h+(size_t)b0*512*128,
          qkvt+(size_t)l*49152, cb+l*384, Qb, Kb, Vtb);
      attn_fused_kernel<<<gA*16,256,0,stream>>>(Qb, Kb, Vtb,
          owt+(size_t)l*16384, cb+1152+l*128, h, cb+3072+l*128, cb+3456+l*128,
          w1t+(size_t)ln*32768, cb+1536+ln*128, UV, part, b0, gA, (l<2)?1:0);
    }
  }
  head_kernel<<<B_,256,0,stream>>>(part,ghw1t,ghw2t,cb,d_out,flag);
}

// Round 11
// 365.070 us; speedup vs baseline: 1.0165x; 1.0016x over previous
//
#include <hip/hip_runtime.h>
#include <cmath>

#define B_   32
#define N_   512
#define E_   8192
#define BN_  16384
#define D_   128

typedef short bf16x8 __attribute__((ext_vector_type(8)));
typedef float f32x4  __attribute__((ext_vector_type(4)));

static __device__ __forceinline__ float bf2f(unsigned short u){
  union{unsigned int i; float f;} v; v.i = ((unsigned int)u)<<16; return v.f;
}
static __device__ __forceinline__ unsigned short f2bf(float f){
  union{unsigned int i; float f;} v; v.f=f;
  unsigned int x=v.i;
  return (unsigned short)((x + 0x7fffu + ((x>>16)&1u))>>16);
}
static __device__ __forceinline__ unsigned int pack2(float a, float b){
  return (unsigned int)f2bf(a) | ((unsigned int)f2bf(b)<<16);
}
// precise GELU (A&S erf, |err|<=1.5e-7) - cold paths
static __device__ __forceinline__ float gelu_f(float x){
  float xs=x*0.70710678118654752f;
  float ax=fabsf(xs);
  float t=__builtin_amdgcn_rcpf(1.0f+0.3275911f*ax);
  float p=t*(0.254829592f+t*(-0.284496736f+t*(1.421413741f+t*(-1.453152027f+t*1.061405429f))));
  float er=1.0f - p*__expf(-ax*ax);
  er = (xs<0.f)? -er : er;
  return 0.5f*x*(1.0f+er);
}
// tanh-form GELU: x/(1+e^{x(c1+c2 x^2)}), |dev from erf-gelu|<=3e-4 (<< bf16 noise) - hot path
static __device__ __forceinline__ float gelu_t(float x){
  float x2=x*x;
  float y=x*(-1.5957691216f + x2*(-0.0713548162f));
  float e=__expf(y);
  return x*__builtin_amdgcn_rcpf(1.0f+e);
}
static __device__ __forceinline__ float ldin(const void* p, size_t i, int isbf){
  return isbf ? bf2f(((const unsigned short*)p)[i]) : ((const float*)p)[i];
}

static __device__ __forceinline__ void block_sum2(float a, float b, float&A, float&Bv, float* red, int nw){
  int lane=threadIdx.x&63, w=threadIdx.x>>6;
  #pragma unroll
  for(int o=32;o>0;o>>=1){ a+=__shfl_down(a,o); b+=__shfl_down(b,o); }
  if(lane==0){ red[w]=a; red[8+w]=b; }
  __syncthreads();
  float sa=0.f, sb=0.f;
  for(int i=0;i<nw;i++){ sa+=red[i]; sb+=red[8+i]; }
  __syncthreads();
  A=sa; Bv=sb;
}

// ---------------- fused sort (hist + scan + scatter) + dtype sniff ----------------
// blocks 0..31 (1024 thr, 16 waves): counting sort of graph g's edges by dst. block 32: sniff.
__global__ __launch_bounds__(1024) void sort_kernel(
  const int* __restrict__ src, const int* __restrict__ dst,
  int* __restrict__ rowptr, unsigned short* __restrict__ ss,
  const unsigned int* __restrict__ xw, int* __restrict__ flag)
{
  int t=threadIdx.x;
  if(blockIdx.x==32){
    if(t<64){
      int cnt=0;
      for(int i=0;i<32;i++){
        unsigned int w=xw[t+64*i];
        float v=bf2f((unsigned short)(w&0xffffu));
        float av=fabsf(v);
        if(v==0.0f || (av>=6e-5f && av<=8.0f)) cnt++;
      }
      #pragma unroll
      for(int o=32;o>0;o>>=1) cnt+=__shfl_down(cnt,o);
      if(t==0) *flag=(cnt>=1024)?1:0;
    }
    return;
  }
  __shared__ int cnts[512];
  __shared__ int offs[512];
  __shared__ int wred[8];
  int g=blockIdx.x;
  if(t<512) cnts[t]=0;
  __syncthreads();
  const int* dg=dst+(size_t)g*E_;
  #pragma unroll
  for(int e=t;e<E_;e+=1024) atomicAdd(&cnts[dg[e]],1);
  __syncthreads();
  // block exclusive scan over 512 counters: threads 0..255, thread t owns {2t, 2t+1}
  if(t<256){
    int lane=t&63, w=t>>6;
    int c0=cnts[2*t], c1=cnts[2*t+1];
    int mysum=c0+c1;
    int sc=mysum;
    #pragma unroll
    for(int o=1;o<64;o<<=1){ int v=__shfl_up(sc,o); if(lane>=o) sc+=v; }
    if(lane==63) wred[w]=sc;
    __syncthreads();
    int wbase=0;
    for(int i=0;i<w;i++) wbase+=wred[i];
    int excl=wbase+sc-mysum;
    rowptr[g*513+2*t  ]=excl;
    rowptr[g*513+2*t+1]=excl+c0;
    offs[2*t  ]=excl;
    offs[2*t+1]=excl+c0;
    if(t==255) rowptr[g*513+512]=wbase+sc;
  } else {
    __syncthreads();
  }
  __syncthreads();
  const int* sg=src+(size_t)g*E_;
  unsigned short* ssg=ss+(size_t)g*E_;
  #pragma unroll
  for(int e=t;e<E_;e+=1024){
    int d=dg[e];
    int pos=atomicAdd(&offs[d],1);
    ssg[pos]=(unsigned short)sg[e];
  }
}

// cb layout (bf16 canonical):
// [0,1152) qkv bias | [1152,1536) ob | [1536,1920) msg_b1 | [1920,2304) msg_b2
// [2304,2688) msg_g | [2688,3072) msg_bb | [3072,3456) attn_g | [3456,3840) attn_b
// [3840,4096) enc_b1 | [4096,4352) enc_g1 | [4352,4608) enc_bn1
// [4608,4736) enc_b2 | [4736,4864) enc_g2 | [4864,4992) enc_bn2
// [4992,5248) gh_b1 | [5248,5504) gh_g | [5504,5760) gh_bn | [5760,5776) gh_b2
__global__ __launch_bounds__(256) void prep_kernel(
  const void* __restrict__ msg_w1, const void* __restrict__ msg_w2,
  const void* __restrict__ qw, const void* __restrict__ kw,
  const void* __restrict__ vw, const void* __restrict__ ow,
  const void* __restrict__ qb, const void* __restrict__ kb, const void* __restrict__ vb,
  const void* __restrict__ ob, const void* __restrict__ msg_b1, const void* __restrict__ msg_b2,
  const void* __restrict__ msg_g, const void* __restrict__ msg_bb,
  const void* __restrict__ attn_g, const void* __restrict__ attn_b,
  const void* __restrict__ enc_w1, const void* __restrict__ enc_w2,
  const void* __restrict__ enc_b1, const void* __restrict__ enc_g1, const void* __restrict__ enc_bn1,
  const void* __restrict__ enc_b2, const void* __restrict__ enc_g2, const void* __restrict__ enc_bn2,
  const void* __restrict__ gh_w1, const void* __restrict__ gh_w2,
  const void* __restrict__ gh_b1, const void* __restrict__ gh_g,
  const void* __restrict__ gh_bn, const void* __restrict__ gh_b2,
  unsigned short* __restrict__ w1t, unsigned short* __restrict__ w2k,
  unsigned short* __restrict__ qkvt, unsigned short* __restrict__ owt,
  unsigned short* __restrict__ w1te, unsigned short* __restrict__ w2te,
  unsigned short* __restrict__ ghw1t, unsigned short* __restrict__ ghw2t,
  unsigned short* __restrict__ cb, const int* __restrict__ flag)
{
  int isbf=*flag;
  int job=blockIdx.y;
  int i=blockIdx.x*256+threadIdx.x;
  if(job<3){ // msg_w1[l] [256][128] -> [128][256] n-major
    if(i<32768){ int l=job; int k=i>>7, n=i&127; w1t[l*32768 + n*256 + k]=f2bf(ldin(msg_w1,(size_t)l*32768+i,isbf)); }
  } else if(job<6){ // msg_w2[l] straight copy [128k][128n]
    int l=job-3; if(i<16384){ w2k[l*16384 + i]=f2bf(ldin(msg_w2,(size_t)l*16384+i,isbf)); }
  } else if(job<15){
    int r=job-6, l=r/3, which=r%3;
    if(i<16384){ int k=i>>7, n=i&127;
      const void* w=(which==0)?qw:((which==1)?kw:vw);
      qkvt[l*49152 + (which*128+n)*128 + k]=f2bf(ldin(w,(size_t)l*16384+i,isbf)); }
  } else if(job<18){
    int l=job-15; if(i<16384){ int k=i>>7, n=i&127; owt[l*16384 + n*128 + k]=f2bf(ldin(ow,(size_t)l*16384+i,isbf)); }
  } else if(job==18){
    if(i<3840){
      float v;
      if(i<1152){ int l=i/384, j=i%384, which=j>>7, jj=j&127;
        const void* bb=(which==0)?qb:((which==1)?kb:vb);
        v=ldin(bb,(size_t)l*128+jj,isbf);
      } else {
        int i2=i-1152; int r=i2/384; int rem=i2%384;
        const void* s = (r==0)?ob:((r==1)?msg_b1:((r==2)?msg_b2:((r==3)?msg_g:((r==4)?msg_bb:((r==5)?attn_g:attn_b)))));
        v=ldin(s,(size_t)rem,isbf);
      }
      cb[i]=f2bf(v);
    }
  } else if(job==19){
    if(i<1152){
      float v;
      if(i<256)       v=ldin(enc_b1,i,isbf);
      else if(i<512)  v=ldin(enc_g1,i-256,isbf);
      else if(i<768)  v=ldin(enc_bn1,i-512,isbf);
      else if(i<896)  v=ldin(enc_b2,i-768,isbf);
      else if(i<1024) v=ldin(enc_g2,i-896,isbf);
      else            v=ldin(enc_bn2,i-1024,isbf);
      cb[3840+i]=f2bf(v);
    }
  } else if(job==20){
    if(i<16384){ int k=i>>8, n=i&255; w1te[n*64+k]=f2bf(ldin(enc_w1,(size_t)i,isbf)); }
  } else if(job==21){
    if(i<32768){ int k=i>>7, n=i&127; w2te[n*256+k]=f2bf(ldin(enc_w2,(size_t)i,isbf)); }
  } else if(job<26){
    int p=job-22; int j=p*32768+i;
    if(i<32768){ int k=j>>8, n=j&255; ghw1t[n*512+k]=f2bf(ldin(gh_w1,(size_t)j,isbf)); }
  } else {
    if(i<2560){ int k=i/10, n=i%10; ghw2t[n*256+k]=f2bf(ldin(gh_w2,(size_t)i,isbf)); }
    else if(i<2560+778){
      int j=i-2560; float v;
      if(j<256)      v=ldin(gh_b1,j,isbf);
      else if(j<512) v=ldin(gh_g,j-256,isbf);
      else if(j<768) v=ldin(gh_bn,j-512,isbf);
      else           v=ldin(gh_b2,j-768,isbf);
      cb[4992+j]=f2bf(v);
    }
  }
}

// ---------------- fused node encoder (+ layer-0 UV generation); vectorized LDS LN passes ----------------
__global__ __launch_bounds__(256) void enc_kernel(
  const void* __restrict__ x, const unsigned short* __restrict__ w1te,
  const unsigned short* __restrict__ w2te, const unsigned short* __restrict__ cb,
  unsigned short* __restrict__ h, const int* __restrict__ flag,
  const unsigned short* __restrict__ w1t0, unsigned short* __restrict__ UV)
{
  __shared__ __align__(16) unsigned short xs[64][72];
  __shared__ __align__(16) unsigned short t1[64][264];
  int isbf=*flag;
  int m0=blockIdx.x*64;
  int t=threadIdx.x, lane=t&63, w=t>>6, quad=lane>>4, ln=lane&15;
  for(int c2=t;c2<1024;c2+=256){
    int i=c2*4, row=i>>6, col=i&63;
    float v0,v1,v2,v3;
    if(isbf){
      const unsigned short* p=(const unsigned short*)x+(size_t)m0*64+i;
      v0=bf2f(p[0]); v1=bf2f(p[1]); v2=bf2f(p[2]); v3=bf2f(p[3]);
    } else {
      float4 f=*(const float4*)((const float*)x+(size_t)m0*64+i);
      v0=f.x; v1=f.y; v2=f.z; v3=f.w;
    }
    ushort4 o; o.x=f2bf(v0); o.y=f2bf(v1); o.z=f2bf(v2); o.w=f2bf(v3);
    *(ushort4*)&xs[row][col]=o;
  }
  __syncthreads();
  f32x4 a[4][4];
  #pragma unroll
  for(int nt=0;nt<4;nt++){ a[nt][0]={0,0,0,0}; a[nt][1]={0,0,0,0}; a[nt][2]={0,0,0,0}; a[nt][3]={0,0,0,0}; }
  #pragma unroll
  for(int k0i=0;k0i<2;k0i++){
    bf16x8 af[4];
    #pragma unroll
    for(int f=0;f<4;f++) af[f]=*(const bf16x8*)(&xs[f*16+ln][k0i*32+quad*8]);
    #pragma unroll
    for(int nt=0;nt<4;nt++){
      int n=w*64+nt*16+ln;
      bf16x8 bfr=*(const bf16x8*)(w1te+(size_t)n*64+k0i*32+quad*8);
      #pragma unroll
      for(int f=0;f<4;f++) a[nt][f]=__builtin_amdgcn_mfma_f32_16x16x32_bf16(af[f],bfr,a[nt][f],0,0,0);
    }
  }
  #pragma unroll
  for(int nt=0;nt<4;nt++){
    int n=w*64+nt*16+ln;
    float bv=bf2f(cb[3840+n]);
    #pragma unroll
    for(int f=0;f<4;f++)
      #pragma unroll
      for(int r=0;r<4;r++) t1[f*16+quad*4+r][n]=f2bf(a[nt][f][r]+bv);
  }
  __syncthreads();
  {
    int row=t>>2, qq=t&3;
    float s=0.f,s2=0.f;
    #pragma unroll
    for(int c8=0;c8<8;c8++){
      bf16x8 v8=*(const bf16x8*)(&t1[row][qq*64+c8*8]);
      const unsigned short* vp=(const unsigned short*)&v8;
      #pragma unroll
      for(int j=0;j<8;j++){ float v=bf2f(vp[j]); s+=v; s2+=v*v; }
    }
    s+=__shfl_xor(s,1); s+=__shfl_xor(s,2);
    s2+=__shfl_xor(s2,1); s2+=__shfl_xor(s2,2);
    float mu=s*(1.f/256.f), var=fmaxf(s2*(1.f/256.f)-mu*mu,0.f);
    float rr=rsqrtf(var+1e-5f);
    #pragma unroll
    for(int c8=0;c8<8;c8++){
      int c0=qq*64+c8*8;
      bf16x8 v8=*(const bf16x8*)(&t1[row][c0]);
      const unsigned short* vp=(const unsigned short*)&v8;
      bf16x8 o8;
      unsigned short* op=(unsigned short*)&o8;
      #pragma unroll
      for(int j=0;j<8;j++){
        float v=bf2f(vp[j]);
        op[j]=f2bf(gelu_f((v-mu)*rr*bf2f(cb[4096+c0+j])+bf2f(cb[4352+c0+j])));
      }
      *(bf16x8*)(&t1[row][c0])=o8;
    }
  }
  __syncthreads();
  f32x4 b2a[2][4];
  #pragma unroll
  for(int nt=0;nt<2;nt++){ b2a[nt][0]={0,0,0,0}; b2a[nt][1]={0,0,0,0}; b2a[nt][2]={0,0,0,0}; b2a[nt][3]={0,0,0,0}; }
  #pragma unroll
  for(int k0i=0;k0i<8;k0i++){
    bf16x8 af[4];
    #pragma unroll
    for(int f=0;f<4;f++) af[f]=*(const bf16x8*)(&t1[f*16+ln][k0i*32+quad*8]);
    #pragma unroll
    for(int nt=0;nt<2;nt++){
      int n=w*32+nt*16+ln;
      bf16x8 bfr=*(const bf16x8*)(w2te+(size_t)n*256+k0i*32+quad*8);
      #pragma unroll
      for(int f=0;f<4;f++) b2a[nt][f]=__builtin_amdgcn_mfma_f32_16x16x32_bf16(af[f],bfr,b2a[nt][f],0,0,0);
    }
  }
  __syncthreads();
  float* mf=(float*)&t1[0][0];   // [64][132]
  #pragma unroll
  for(int nt=0;nt<2;nt++){
    int n=w*32+nt*16+ln;
    float bv=bf2f(cb[4608+n]);
    #pragma unroll
    for(int f=0;f<4;f++)
      #pragma unroll
      for(int r=0;r<4;r++) mf[(f*16+quad*4+r)*132+n]=b2a[nt][f][r]+bv;
  }
  __syncthreads();
  {
    int row=t>>2, qq=t&3;
    float vals[32];
    float s=0.f,s2=0.f;
    #pragma unroll
    for(int c4=0;c4<8;c4++){
      float4 v4=*(const float4*)(&mf[row*132+qq*32+c4*4]);
      vals[c4*4+0]=v4.x; vals[c4*4+1]=v4.y; vals[c4*4+2]=v4.z; vals[c4*4+3]=v4.w;
      s+=v4.x; s+=v4.y; s+=v4.z; s+=v4.w;
      s2+=v4.x*v4.x; s2+=v4.y*v4.y; s2+=v4.z*v4.z; s2+=v4.w*v4.w;
    }
    s+=__shfl_xor(s,1); s+=__shfl_xor(s,2);
    s2+=__shfl_xor(s2,1); s2+=__shfl_xor(s2,2);
    float mu=s*(1.f/128.f), var=fmaxf(s2*(1.f/128.f)-mu*mu,0.f);
    float rr=rsqrtf(var+1e-5f);
    #pragma unroll
    for(int c8=0;c8<4;c8++){
      int c=qq*32+c8*8;
      bf16x8 o8; unsigned short* op=(unsigned short*)&o8;
      #pragma unroll
      for(int j=0;j<8;j++){
        float v=(vals[c8*8+j]-mu)*rr*bf2f(cb[4736+c+j])+bf2f(cb[4864+c+j]);
        op[j]=f2bf(v);
        vals[c8*8+j]=v;
      }
      *(bf16x8*)(h+(size_t)(m0+row)*128+c)=o8;
    }
    __syncthreads();   // all mf reads done before t1 reuse as hb
    unsigned short* hb=&t1[0][0];  // [64][136] bf16
    #pragma unroll
    for(int c8=0;c8<4;c8++){
      bf16x8 o8; unsigned short* op=(unsigned short*)&o8;
      #pragma unroll
      for(int j=0;j<8;j++) op[j]=f2bf(vals[c8*8+j]);
      *(bf16x8*)(&hb[row*136+qq*32+c8*8])=o8;
    }
  }
  __syncthreads();
  // ---- fused uvgen for layer 0: UV[m0..m0+64) = [h@W1a+b1 | h@W1b] ----
  {
    const unsigned short* hb=&t1[0][0];
    #pragma unroll
    for(int y=0;y<2;y++)
    #pragma unroll
    for(int nt=0;nt<2;nt++){
      int n=w*32+nt*16+ln;
      f32x4 a0={0,0,0,0},a1={0,0,0,0},a2={0,0,0,0},a3={0,0,0,0};
      const unsigned short* wp=w1t0+(size_t)n*256+y*128+quad*8;
      #pragma unroll
      for(int k0=0;k0<128;k0+=32){
        bf16x8 bfr=*(const bf16x8*)(wp+k0);
        bf16x8 f0=*(const bf16x8*)(hb+(size_t)(ln   )*136+k0+quad*8);
        bf16x8 f1=*(const bf16x8*)(hb+(size_t)(16+ln)*136+k0+quad*8);
        bf16x8 f2=*(const bf16x8*)(hb+(size_t)(32+ln)*136+k0+quad*8);
        bf16x8 f3=*(const bf16x8*)(hb+(size_t)(48+ln)*136+k0+quad*8);
        a0=__builtin_amdgcn_mfma_f32_16x16x32_bf16(f0,bfr,a0,0,0,0);
        a1=__builtin_amdgcn_mfma_f32_16x16x32_bf16(f1,bfr,a1,0,0,0);
        a2=__builtin_amdgcn_mfma_f32_16x16x32_bf16(f2,bfr,a2,0,0,0);
        a3=__builtin_amdgcn_mfma_f32_16x16x32_bf16(f3,bfr,a3,0,0,0);
      }
      float bv=y?0.f:bf2f(cb[1536+n]);
      #pragma unroll
      for(int r=0;r<4;r++){
        UV[(size_t)(m0   +quad*4+r)*256+y*128+n]=f2bf(a0[r]+bv);
        UV[(size_t)(m0+16+quad*4+r)*256+y*128+n]=f2bf(a1[r]+bv);
        UV[(size_t)(m0+32+quad*4+r)*256+y*128+n]=f2bf(a2[r]+bv);
        UV[(size_t)(m0+48+quad*4+r)*256+y*128+n]=f2bf(a3[r]+bv);
      }
    }
  }
}

// ---------------- QKV generation: Q (pre-scaled, row-major), K (row-major), V^T ----------------
// grid (gA*8, 3): y=0 -> Q, y=1 -> K, y=2 -> V written transposed [g][128 dims][512 keys]
__global__ __launch_bounds__(256) void qkvgen_kernel(
  const unsigned short* __restrict__ hrows, const unsigned short* __restrict__ wqkv,
  const unsigned short* __restrict__ bqkv,
  unsigned short* __restrict__ Qb, unsigned short* __restrict__ Kb,
  unsigned short* __restrict__ Vtb)
{
  __shared__ __align__(16) unsigned short a_t[64][136];
  int t=threadIdx.x;
  int m0=blockIdx.x*64;
  int y=blockIdx.y;
  for(int c=t;c<1024;c+=256){
    int m=c>>4, pp=c&15;
    *(uint4*)&a_t[m][pp*8]=*((const uint4*)(hrows+(size_t)(m0+m)*128)+pp);
  }
  __syncthreads();
  int lane=t&63, w=t>>6, quad=lane>>4, ln=lane&15;
  int gloc=m0>>9, r0=m0&511;
  #pragma unroll
  for(int nt=0;nt<2;nt++){
    int n=w*32+nt*16+ln;
    f32x4 a0={0,0,0,0},a1={0,0,0,0},a2={0,0,0,0},a3={0,0,0,0};
    const unsigned short* wp=wqkv+(size_t)(y*128+n)*128+quad*8;
    #pragma unroll
    for(int k0=0;k0<128;k0+=32){
      bf16x8 bfr=*(const bf16x8*)(wp+k0);
      bf16x8 f0=*(const bf16x8*)(&a_t[ln   ][k0+quad*8]);
      bf16x8 f1=*(const bf16x8*)(&a_t[16+ln][k0+quad*8]);
      bf16x8 f2=*(const bf16x8*)(&a_t[32+ln][k0+quad*8]);
      bf16x8 f3=*(const bf16x8*)(&a_t[48+ln][k0+quad*8]);
      a0=__builtin_amdgcn_mfma_f32_16x16x32_bf16(f0,bfr,a0,0,0,0);
      a1=__builtin_amdgcn_mfma_f32_16x16x32_bf16(f1,bfr,a1,0,0,0);
      a2=__builtin_amdgcn_mfma_f32_16x16x32_bf16(f2,bfr,a2,0,0,0);
      a3=__builtin_amdgcn_mfma_f32_16x16x32_bf16(f3,bfr,a3,0,0,0);
    }
    float bv=bf2f(bqkv[y*128+n]);
    if(y==0){
      const float sc=0.17677669529663689f;
      #pragma unroll
      for(int r=0;r<4;r++){
        Qb[(size_t)(m0   +quad*4+r)*128+n]=f2bf((a0[r]+bv)*sc);
        Qb[(size_t)(m0+16+quad*4+r)*128+n]=f2bf((a1[r]+bv)*sc);
        Qb[(size_t)(m0+32+quad*4+r)*128+n]=f2bf((a2[r]+bv)*sc);
        Qb[(size_t)(m0+48+quad*4+r)*128+n]=f2bf((a3[r]+bv)*sc);
      }
    } else if(y==1){
      #pragma unroll
      for(int r=0;r<4;r++){
        Kb[(size_t)(m0   +quad*4+r)*128+n]=f2bf(a0[r]+bv);
        Kb[(size_t)(m0+16+quad*4+r)*128+n]=f2bf(a1[r]+bv);
        Kb[(size_t)(m0+32+quad*4+r)*128+n]=f2bf(a2[r]+bv);
        Kb[(size_t)(m0+48+quad*4+r)*128+n]=f2bf(a3[r]+bv);
      }
    } else {
      unsigned short* vrow = Vtb + ((size_t)gloc*128+n)*512 + r0 + quad*4;
      ushort4 o;
      o.x=f2bf(a0[0]+bv); o.y=f2bf(a0[1]+bv); o.z=f2bf(a0[2]+bv); o.w=f2bf(a0[3]+bv);
      *(ushort4*)(vrow)=o;
      o.x=f2bf(a1[0]+bv); o.y=f2bf(a1[1]+bv); o.z=f2bf(a1[2]+bv); o.w=f2bf(a1[3]+bv);
      *(ushort4*)(vrow+16)=o;
      o.x=f2bf(a2[0]+bv); o.y=f2bf(a2[1]+bv); o.z=f2bf(a2[2]+bv); o.w=f2bf(a2[3]+bv);
      *(ushort4*)(vrow+32)=o;
      o.x=f2bf(a3[0]+bv); o.y=f2bf(a3[1]+bv); o.z=f2bf(a3[2]+bv); o.w=f2bf(a3[3]+bv);
      *(ushort4*)(vrow+48)=o;
    }
  }
}

// ---------------- fused edge phase: branchless gather (fast gelu) + k-split GEMV ----------------
__global__ __launch_bounds__(128) void edgef_kernel(
  unsigned short* __restrict__ h,
  const unsigned short* __restrict__ UV,      // full rows [B*512][256], global-g indexed
  const unsigned short* __restrict__ ss,
  const int* __restrict__ rowptr,
  const unsigned short* __restrict__ w2k,     // [128k][128n]
  const unsigned short* __restrict__ b2,
  const unsigned short* __restrict__ gg, const unsigned short* __restrict__ bbp,
  int b0, int gEp)
{
  __shared__ __align__(16) float aggL[2][4][128];
  __shared__ __align__(16) float po[2][4][128];
  int t=threadIdx.x, lane=t&63, w=t>>6;
  int bid=blockIdx.x;
  int lg=bid%gEp, ch=bid/gEp;     // ch in [0,128): 4-dst chunk
  int g=b0+lg;
  const unsigned short* UVg = UV + (size_t)g*512*256;
  const unsigned short* ssg = ss + (size_t)g*E_;
  int dbase = ch*4;
  int bnd[5];
  #pragma unroll
  for(int i=0;i<5;i++) bnd[i]=rowptr[g*513+dbase+i];
  // ---- gather: wave w takes its half of each dst's edge range (branchless, masked idx) ----
  #pragma unroll 1
  for(int dd=0;dd<4;dd++){
    int e_lo=bnd[dd], e_hi0=bnd[dd+1];
    int half=(e_hi0-e_lo+1)>>1;
    int es = w ? (e_lo+half) : e_lo;
    int ee = w ? e_hi0       : (e_lo+half);
    unsigned int vdw=*(const unsigned int*)(UVg + (size_t)(dbase+dd)*256 + 128 + lane*2);
    float v0=bf2f((unsigned short)(vdw&0xffffu)), v1=bf2f((unsigned short)(vdw>>16));
    float a0=0.f, a1=0.f;
    int si3,si4,si5;
    unsigned int u0,u1,u2;
    {
      // over-reads (<=6 u16 past range) stay in-ws; idx masked &511
      int s0=__builtin_amdgcn_readfirstlane((int)ssg[es  ])&511;
      int s1=__builtin_amdgcn_readfirstlane((int)ssg[es+1])&511;
      int s2=__builtin_amdgcn_readfirstlane((int)ssg[es+2])&511;
      si3=(int)ssg[es+3]; si4=(int)ssg[es+4]; si5=(int)ssg[es+5];
      u0=*(const unsigned int*)(UVg + (size_t)s0*256 + lane*2);
      u1=*(const unsigned int*)(UVg + (size_t)s1*256 + lane*2);
      u2=*(const unsigned int*)(UVg + (size_t)s2*256 + lane*2);
    }
    #pragma unroll 2
    for(int e=es;e<ee;e++){
      float z0=bf2f((unsigned short)(u0&0xffffu))+v0;
      float z1=bf2f((unsigned short)(u0>>16))+v1;
      u0=u1; u1=u2;
      int s3=__builtin_amdgcn_readfirstlane(si3)&511;
      u2=*(const unsigned int*)(UVg + (size_t)s3*256 + lane*2);
      si3=si4; si4=si5;
      si5=(int)ssg[e+6];
      a0+=gelu_t(z0); a1+=gelu_t(z1);
    }
    aggL[w][dd][lane*2  ]=a0;
    aggL[w][dd][lane*2+1]=a1;
  }
  __syncthreads();
  // ---- GEMV k-split: wave w does all 4 dst over k in [w*64, w*64+64) ----
  float o[4][2];
  #pragma unroll
  for(int dd=0;dd<4;dd++){ o[dd][0]=0.f; o[dd][1]=0.f; }
  #pragma unroll 4
  for(int kk=0;kk<64;kk++){
    int k=w*64+kk;
    unsigned int wdw=*(const unsigned int*)(w2k+(size_t)k*128+lane*2);
    float w0=bf2f((unsigned short)(wdw&0xffffu));
    float w1=bf2f((unsigned short)(wdw>>16));
    #pragma unroll
    for(int dd=0;dd<4;dd++){
      float av=aggL[0][dd][k]+aggL[1][dd][k];
      o[dd][0]+=av*w0; o[dd][1]+=av*w1;
    }
  }
  #pragma unroll
  for(int dd=0;dd<4;dd++){
    po[w][dd][lane*2  ]=o[dd][0];
    po[w][dd][lane*2+1]=o[dd][1];
  }
  __syncthreads();
  // ---- combine partials + deg*b2 + residual + LN: wave w owns dst pair {2w, 2w+1} ----
  #pragma unroll 1
  for(int p=0;p<2;p++){
    int di=w*2+p;
    int d = dbase + di;
    float deg=(float)(bnd[di+1]-bnd[di]);
    float o0=bf2f(b2[lane*2  ])*deg + po[0][di][lane*2  ] + po[1][di][lane*2  ];
    float o1=bf2f(b2[lane*2+1])*deg + po[0][di][lane*2+1] + po[1][di][lane*2+1];
    size_t base=(size_t)(g*512+d)*128;
    unsigned int hdw=*(const unsigned int*)(h+base+lane*2);
    float x0=bf2f((unsigned short)(hdw&0xffffu))+o0;
    float x1=bf2f((unsigned short)(hdw>>16))+o1;
    float s1=x0+x1, s2=x0*x0+x1*x1;
    #pragma unroll
    for(int off=32;off>0;off>>=1){ s1+=__shfl_xor(s1,off); s2+=__shfl_xor(s2,off); }
    float mu=s1*(1.f/128.f), var=fmaxf(s2*(1.f/128.f)-mu*mu,0.f);
    float rr=rsqrtf(var+1e-5f);
    float y0=(x0-mu)*rr*bf2f(gg[lane*2  ])+bf2f(bbp[lane*2  ]);
    float y1=(x1-mu)*rr*bf2f(gg[lane*2+1])+bf2f(bbp[lane*2+1]);
    *(unsigned int*)(h+base+lane*2)=pack2(y0,y1);
  }
}

// ---------------- fused flash attention + oproj + residual/LN + next-layer uvgen / pool partials ----------------
// grid gA*16: block = (graph lg, 32-row tile ch). wave w = head w. barrier-free flash.
// Psh double-buffered by qt-parity. s_setprio(1) wraps all MFMA clusters (T5).
__global__ __launch_bounds__(256) void attn_fused_kernel(
  const unsigned short* __restrict__ Qb, const unsigned short* __restrict__ Kb,
  const unsigned short* __restrict__ Vtb,
  const unsigned short* __restrict__ wo, const unsigned short* __restrict__ bo,
  unsigned short* __restrict__ h,
  const unsigned short* __restrict__ gg, const unsigned short* __restrict__ bbp,
  const unsigned short* __restrict__ w1tn, const unsigned short* __restrict__ b1n,
  unsigned short* __restrict__ UV, float* part, int b0, int gA, int do_uv)
{
  __shared__ __align__(16) unsigned short hO[32][136];
  __shared__ __align__(16) unsigned short Psh[2][4][16][72];
  __shared__ __align__(16) float mf[32][132];
  int bx=blockIdx.x;
  int lg=bx%gA, ch=bx/gA;           // ch in [0,16)
  int r0=ch*32;
  int g=b0+lg;
  int t=threadIdx.x, lane=t&63, w=t>>6, quad=lane>>4, ln=lane&15;
  const unsigned short* Qg = Qb + (size_t)lg*65536;
  const unsigned short* Kg = Kb + (size_t)lg*65536 + w*32;
  const unsigned short* Vg = Vtb + ((size_t)lg*128 + w*32)*512;
  // ---- flash: wave w = head w, rows [r0, r0+32) ----
  bf16x8 qf[2];
  #pragma unroll
  for(int qt=0;qt<2;qt++)
    qf[qt]=*(const bf16x8*)(Qg + (size_t)(r0+qt*16+ln)*128 + w*32 + quad*8);
  f32x4 O[2][2]; float Lp[2][4];
  #pragma unroll
  for(int qt=0;qt<2;qt++){ O[qt][0]={0,0,0,0}; O[qt][1]={0,0,0,0};
    #pragma unroll
    for(int r=0;r<4;r++) Lp[qt][r]=0.f; }
  for(int kc=0;kc<8;kc++){
    bf16x8 kf[4];
    #pragma unroll
    for(int f=0;f<4;f++) kf[f]=*(const bf16x8*)(Kg + (size_t)(kc*64+f*16+ln)*128 + quad*8);
    bf16x8 va[2], vb[2];
    #pragma unroll
    for(int s2=0;s2<2;s2++){
      va[s2]=*(const bf16x8*)(Vg + (size_t)ln*512      + kc*64 + s2*32 + quad*8);
      vb[s2]=*(const bf16x8*)(Vg + (size_t)(16+ln)*512 + kc*64 + s2*32 + quad*8);
    }
    #pragma unroll
    for(int qt=0;qt<2;qt++){
      f32x4 s[4];
      __builtin_amdgcn_s_setprio(1);
      #pragma unroll
      for(int f=0;f<4;f++){
        f32x4 z={0,0,0,0};
        s[f]=__builtin_amdgcn_mfma_f32_16x16x32_bf16(qf[qt],kf[f],z,0,0,0);
      }
      __builtin_amdgcn_s_setprio(0);
      #pragma unroll
      for(int f=0;f<4;f++)
        #pragma unroll
        for(int r=0;r<4;r++){
          float pe=__expf(fminf(s[f][r],30.0f));
          Psh[qt][w][quad*4+r][f*16+ln]=f2bf(pe);
          Lp[qt][r]+=pe;
        }
      __builtin_amdgcn_s_setprio(1);
      #pragma unroll
      for(int s2=0;s2<2;s2++){
        bf16x8 pf=*(const bf16x8*)(&Psh[qt][w][ln][s2*32+quad*8]);
        O[qt][0]=__builtin_amdgcn_mfma_f32_16x16x32_bf16(pf,va[s2],O[qt][0],0,0,0);
        O[qt][1]=__builtin_amdgcn_mfma_f32_16x16x32_bf16(pf,vb[s2],O[qt][1],0,0,0);
      }
      __builtin_amdgcn_s_setprio(0);
    }
  }
  #pragma unroll
  for(int qt=0;qt<2;qt++){
    #pragma unroll
    for(int o=1;o<16;o<<=1)
      #pragma unroll
      for(int r=0;r<4;r++) Lp[qt][r]+=__shfl_xor(Lp[qt][r],o);
    #pragma unroll
    for(int r=0;r<4;r++){
      float inv=1.0f/Lp[qt][r];
      int qr=qt*16+quad*4+r;
      hO[qr][w*32+ln   ]=f2bf(O[qt][0][r]*inv);
      hO[qr][w*32+16+ln]=f2bf(O[qt][1][r]*inv);
    }
  }
  __syncthreads();
  // ---- oproj GEMM on the 32-row tile ----
  #pragma unroll
  for(int nt=0;nt<2;nt++){
    int n=w*32+nt*16+ln;
    f32x4 a0={0,0,0,0},a1={0,0,0,0};
    const unsigned short* wp=wo+(size_t)n*128+quad*8;
    __builtin_amdgcn_s_setprio(1);
    #pragma unroll
    for(int k0=0;k0<128;k0+=32){
      bf16x8 bfr=*(const bf16x8*)(wp+k0);
      bf16x8 f0=*(const bf16x8*)(&hO[ln   ][k0+quad*8]);
      bf16x8 f1=*(const bf16x8*)(&hO[16+ln][k0+quad*8]);
      a0=__builtin_amdgcn_mfma_f32_16x16x32_bf16(f0,bfr,a0,0,0,0);
      a1=__builtin_amdgcn_mfma_f32_16x16x32_bf16(f1,bfr,a1,0,0,0);
    }
    __builtin_amdgcn_s_setprio(0);
    float bv=bf2f(bo[n]);
    #pragma unroll
    for(int r=0;r<4;r++){
      mf[quad*4+r   ][n]=a0[r]+bv;
      mf[16+quad*4+r][n]=a1[r]+bv;
    }
  }
  __syncthreads();
  // ---- residual + LN; write h, refill hO (bf16) and mf (f32) with new-h ----
  {
    int row=t>>3, oct=t&7;
    size_t base=((size_t)(g*512+r0+row))*128;
    float vals[16];
    float s=0.f,s2=0.f;
    for(int j=0;j<16;j++){
      int c=oct*16+j;
      float v=bf2f(h[base+c])+mf[row][c];
      vals[j]=v; s+=v; s2+=v*v;
    }
    s+=__shfl_xor(s,1); s+=__shfl_xor(s,2); s+=__shfl_xor(s,4);
    s2+=__shfl_xor(s2,1); s2+=__shfl_xor(s2,2); s2+=__shfl_xor(s2,4);
    float mu=s*(1.f/128.f), var=fmaxf(s2*(1.f/128.f)-mu*mu,0.f);
    float rr=rsqrtf(var+1e-5f);
    for(int j=0;j<16;j+=2){
      int c=oct*16+j;
      float y0=(vals[j]  -mu)*rr*bf2f(gg[c  ])+bf2f(bbp[c  ]);
      float y1=(vals[j+1]-mu)*rr*bf2f(gg[c+1])+bf2f(bbp[c+1]);
      *(unsigned int*)(h+base+c)=pack2(y0,y1);
      hO[row][c]=f2bf(y0); hO[row][c+1]=f2bf(y1);
      mf[row][c]=y0; mf[row][c+1]=y1;
    }
  }
  __syncthreads();
  if(!do_uv){
    // ---- pool partials for this 32-row tile ----
    if(t<128){
      float s=0.f,s2=0.f,mx=-1e30f;
      for(int r=0;r<32;r++){ float v=mf[r][t]; s+=v; s2+=v*v; mx=fmaxf(mx,v); }
      size_t pb=((size_t)(g*16+ch))*384;
      part[pb+t]=s; part[pb+128+t]=s2; part[pb+256+t]=mx;
    }
    return;
  }
  // ---- next-layer uvgen on the 32-row tile ----
  #pragma unroll
  for(int y=0;y<2;y++)
  #pragma unroll
  for(int nt=0;nt<2;nt++){
    int n=w*32+nt*16+ln;
    f32x4 a0={0,0,0,0},a1={0,0,0,0};
    const unsigned short* wp=w1tn+(size_t)n*256+y*128+quad*8;
    __builtin_amdgcn_s_setprio(1);
    #pragma unroll
    for(int k0=0;k0<128;k0+=32){
      bf16x8 bfr=*(const bf16x8*)(wp+k0);
      bf16x8 f0=*(const bf16x8*)(&hO[ln   ][k0+quad*8]);
      bf16x8 f1=*(const bf16x8*)(&hO[16+ln][k0+quad*8]);
      a0=__builtin_amdgcn_mfma_f32_16x16x32_bf16(f0,bfr,a0,0,0,0);
      a1=__builtin_amdgcn_mfma_f32_16x16x32_bf16(f1,bfr,a1,0,0,0);
    }
    __builtin_amdgcn_s_setprio(0);
    float bv=y?0.f:bf2f(b1n[n]);
    size_t rb=(size_t)(g*512+r0);
    #pragma unroll
    for(int r=0;r<4;r++){
      UV[(rb   +quad*4+r)*256+y*128+n]=f2bf(a0[r]+bv);
      UV[(rb+16+quad*4+r)*256+y*128+n]=f2bf(a1[r]+bv);
    }
  }
}

// ---------------- graph head: finalize pooling + MLP ----------------
__global__ __launch_bounds__(256) void head_kernel(
  const float* __restrict__ part, const unsigned short* __restrict__ ghw1t,
  const unsigned short* __restrict__ ghw2t, const unsigned short* __restrict__ cb,
  void* __restrict__ out, const int* __restrict__ flag)
{
  int isbf=*flag;
  int b=blockIdx.x, t=threadIdx.x;
  __shared__ float pl[512];
  __shared__ float gl[256];
  __shared__ float red[16];
  if(t<128){
    float s=0.f,s2=0.f,mx=-1e30f;
    for(int c=0;c<16;c++){
      size_t base=((size_t)(b*16+c))*384;
      s += part[base+t];
      s2+= part[base+128+t];
      mx = fmaxf(mx, part[base+256+t]);
    }
    float mean=s*(1.f/512.f);
    float var=fmaxf(s2*(1.f/512.f)-mean*mean,0.f);
    float sd=sqrtf(var+1e-6f);
    pl[t]=mean; pl[128+t]=s; pl[256+t]=mx; pl[384+t]=sd;
  }
  __syncthreads();
  float a=bf2f(cb[4992+t]);
  const unsigned short* wr=ghw1t+(size_t)t*512;
  for(int k0=0;k0<512;k0+=8){
    bf16x8 wv=*(const bf16x8*)(wr+k0);
    const unsigned short* wp=(const unsigned short*)&wv;
    #pragma unroll
    for(int j=0;j<8;j++) a+=pl[k0+j]*bf2f(wp[j]);
  }
  float u=gelu_f(a);
  float S,S2; block_sum2(u,u*u,S,S2,red,4);
  float mu=S*(1.f/256.f), var=fmaxf(S2*(1.f/256.f)-mu*mu,0.f);
  float r=rsqrtf(var+1e-5f);
  gl[t]=(u-mu)*r*bf2f(cb[5248+t])+bf2f(cb[5504+t]);
  __syncthreads();
  if(t<10){
    float o=bf2f(cb[5760+t]);
    const unsigned short* wr2=ghw2t+(size_t)t*256;
    for(int k0=0;k0<256;k0+=8){
      bf16x8 wv=*(const bf16x8*)(wr2+k0);
      const unsigned short* wp=(const unsigned short*)&wv;
      #pragma unroll
      for(int j=0;j<8;j++) o+=gl[k0+j]*bf2f(wp[j]);
    }
    if(isbf) ((unsigned short*)out)[b*10+t]=f2bf(o);
    else     ((float*)out)[b*10+t]=o;
  }
}

extern "C" void kernel_launch(void* const* d_in, const int* in_sizes, int n_in,
                              void* d_out, int out_size, void* d_ws, size_t ws_size,
                              hipStream_t stream)
{
  const void* x      =d_in[0];
  const int*  src    =(const int*)d_in[1];
  const int*  dstp   =(const int*)d_in[2];
  const void* enc_w1 =d_in[3];  const void* enc_b1 =d_in[4];
  const void* enc_g1 =d_in[5];  const void* enc_bn1=d_in[6];
  const void* enc_w2 =d_in[7];  const void* enc_b2 =d_in[8];
  const void* enc_g2 =d_in[9];  const void* enc_bn2=d_in[10];
  const void* msg_w1 =d_in[11]; const void* msg_b1 =d_in[12];
  const void* msg_w2 =d_in[13]; const void* msg_b2 =d_in[14];
  const void* msg_g  =d_in[15]; const void* msg_bb =d_in[16];
  const void* qw     =d_in[17]; const void* qb     =d_in[18];
  const void* kw     =d_in[19]; const void* kb     =d_in[20];
  const void* vw     =d_in[21]; const void* vb     =d_in[22];
  const void* ow     =d_in[23]; const void* ob     =d_in[24];
  const void* attn_g =d_in[25]; const void* attn_b =d_in[26];
  const void* gh_w1  =d_in[27]; const void* gh_b1  =d_in[28];
  const void* gh_g   =d_in[29]; const void* gh_bn  =d_in[30];
  const void* gh_w2  =d_in[31]; const void* gh_b2  =d_in[32];
  (void)in_sizes; (void)n_in; (void)out_size;

  char* base=(char*)d_ws;
  unsigned short* h    =(unsigned short*)(base);                 // 4 MB
  unsigned short* w1t  =(unsigned short*)(base + 4194304);
  unsigned short* w2k  =(unsigned short*)(base + 4390912);
  unsigned short* qkvt =(unsigned short*)(base + 4489216);
  unsigned short* owt  =(unsigned short*)(base + 4784128);
  unsigned short* w1te =(unsigned short*)(base + 4882432);
  unsigned short* w2te =(unsigned short*)(base + 4915200);
  unsigned short* ghw1t=(unsigned short*)(base + 4980736);
  unsigned short* ghw2t=(unsigned short*)(base + 5242880);
  unsigned short* cb   =(unsigned short*)(base + 5248000);
  int*   rowptr        =(int*)(base + 5325312);                  // 65664 B
  int*   flag          =(int*)(base + 5390976);
  unsigned short* ssrt =(unsigned short*)(base + 5505024);       // 512 KB (+edgef over-reads land in R)
  char* R              = base + 6029312;                          // shared region

  // R layout: UV (full, 8 MB) | Qb | Kb | Vtb  (per attn pass, gA graphs each)
  size_t Rcap = (ws_size > 6029312) ? (ws_size - 6029312) : 0;
  int gA = 32;
  while(gA > 4 && 8388608 + (size_t)gA*393216 > Rcap) gA >>= 1;
  int apass = 32/gA;
  unsigned short* UV  =(unsigned short*)R;                  // 16384 x 256 bf16 = 8 MB
  unsigned short* Qb  =UV  + 4194304;                       // gA*512*128 bf16
  unsigned short* Kb  =Qb  + (size_t)gA*65536;
  unsigned short* Vtb =Kb  + (size_t)gA*65536;
  float* part=(float*)R;   // pool partials: 32*16*384*4 = 786 KB (UV region free during l==2 attn)

  sort_kernel<<<33,1024,0,stream>>>(src,dstp,rowptr,ssrt,(const unsigned int*)x,flag);
  prep_kernel<<<dim3(128,27),256,0,stream>>>(msg_w1,msg_w2,qw,kw,vw,ow,qb,kb,vb,
      ob,msg_b1,msg_b2,msg_g,msg_bb,attn_g,attn_b,
      enc_w1,enc_w2,enc_b1,enc_g1,enc_bn1,enc_b2,enc_g2,enc_bn2,
      gh_w1,gh_w2,gh_b1,gh_g,gh_bn,gh_b2,
      w1t,w2k,qkvt,owt,w1te,w2te,ghw1t,ghw2t,cb,flag);

  enc_kernel<<<BN_/64,256,0,stream>>>(x,w1te,w2te,cb,h,flag,w1t,UV);

  for(int l=0;l<3;l++){
    edgef_kernel<<<32*128,128,0,stream>>>(h,UV,ssrt,rowptr,
        w2k+(size_t)l*16384, cb+1920+l*128, cb+2304+l*128, cb+2688+l*128, 0, 32);
    int ln=(l+1)%3;
    for(int ap=0;ap<apass;ap++){
      int b0=ap*gA;
      qkvgen_kernel<<<dim3(gA*8,3),256,0,stream>>>(h+(size_t)b0*512*128,
          qkvt+(size_t)l*49152, cb+l*384, Qb, Kb, Vtb);
      attn_fused_kernel<<<gA*16,256,0,stream>>>(Qb, Kb, Vtb,
          owt+(size_t)l*16384, cb+1152+l*128, h, cb+3072+l*128, cb+3456+l*128,
          w1t+(size_t)ln*32768, cb+1536+ln*128, UV, part, b0, gA, (l<2)?1:0);
    }
  }
  head_kernel<<<B_,256,0,stream>>>(part,ghw1t,ghw2t,cb,d_out,flag);
}